// Round 1
// baseline (8054.199 us; speedup 1.0000x reference)
//
#include <hip/hip_runtime.h>

static constexpr int B  = 8;
static constexpr int C  = 64;
static constexpr int CW = 177;   // 2*64+49
static constexpr int H  = 64, W  = 80;     // pooled / feat spatial
static constexpr int H0 = 128, W0 = 160;   // full-res spatial

// ---------------- pool 2x2 mean ----------------
__global__ void pool2_kernel(const float* __restrict__ in, float* __restrict__ out, int n) {
  int idx = blockIdx.x * blockDim.x + threadIdx.x;
  if (idx >= n) return;
  int w = idx % W; int h = (idx / W) % H; int bc = idx / (W * H);
  const float* p = in + ((size_t)bc * H0 + 2 * h) * W0 + 2 * w;
  out[idx] = 0.25f * (p[0] + p[1] + p[W0] + p[W0 + 1]);
}

// ---------------- corr (49 offsets) + concat x,y -> feat (B,177,64,80) ----------------
__global__ void corr_concat_kernel(const float* __restrict__ xp, const float* __restrict__ yp,
                                   const float* __restrict__ x, const float* __restrict__ y,
                                   float* __restrict__ feat) {
  int idx = blockIdx.x * blockDim.x + threadIdx.x;
  if (idx >= B * CW * H * W) return;
  int w = idx % W; int h = (idx / W) % H; int o = (idx / (W * H)) % CW; int b = idx / (W * H * CW);
  float val;
  if (o < 49) {
    int dy = (o / 7) * 2 - 6, dx = (o % 7) * 2 - 6;
    int hh = h + dy, ww = w + dx;
    float s = 0.f;
    if (hh >= 0 && hh < H && ww >= 0 && ww < W) {
      const float* xpp = xp + ((size_t)b * C * H + h) * W + w;
      const float* ypp = yp + ((size_t)b * C * H + hh) * W + ww;
      for (int c = 0; c < C; ++c) s += xpp[c * H * W] * ypp[c * H * W];
    }
    val = s * (1.0f / C);
  } else if (o < 49 + C) {
    val = x[((size_t)(b * C + (o - 49)) * H + h) * W + w];
  } else {
    val = y[((size_t)(b * C + (o - 49 - C)) * H + h) * W + w];
  }
  feat[idx] = val;
}

// ---------------- 5x5 stride-2 pad-2 conv, weights for one oc staged in LDS ----------------
template<int IC, int IH, int IW, int OH, int OW, bool RELU>
__global__ void conv5_s2_kernel(const float* __restrict__ in, const float* __restrict__ wgt,
                                float* __restrict__ out, int OC) {
  constexpr int NT = (OH * OW + 255) / 256;
  int blk = blockIdx.x;
  int tile = blk % NT; int oc = (blk / NT) % OC; int b = blk / (NT * OC);
  extern __shared__ float lw[];
  for (int t = threadIdx.x; t < IC * 25; t += blockDim.x) lw[t] = wgt[(size_t)oc * IC * 25 + t];
  __syncthreads();
  int p = tile * 256 + threadIdx.x;
  if (p >= OH * OW) return;
  int oh = p / OW, ow = p % OW;
  float acc = 0.f;
  const float* ib = in + (size_t)b * IC * IH * IW;
  for (int ic = 0; ic < IC; ++ic) {
    const float* ip = ib + ic * IH * IW;
    const float* wp = lw + ic * 25;
#pragma unroll
    for (int ky = 0; ky < 5; ++ky) {
      int ih = oh * 2 + ky - 2;
      if (ih < 0 || ih >= IH) continue;
#pragma unroll
      for (int kx = 0; kx < 5; ++kx) {
        int iw = ow * 2 + kx - 2;
        if (iw < 0 || iw >= IW) continue;
        acc += ip[ih * IW + iw] * wp[ky * 5 + kx];
      }
    }
  }
  if (RELU) acc = fmaxf(acc, 0.f);
  out[((size_t)(b * OC + oc) * OH + oh) * OW + ow] = acc;
}

// ---------------- 3x3 stride-2 pad-1 conv (naive, small) ----------------
template<int IC, int IH, int IW, int OH, int OW>
__global__ void conv3_s2_kernel(const float* __restrict__ in, const float* __restrict__ wgt,
                                float* __restrict__ out, int OC) {
  int idx = blockIdx.x * blockDim.x + threadIdx.x;
  if (idx >= B * OC * OH * OW) return;
  int ow = idx % OW; int oh = (idx / OW) % OH; int oc = (idx / (OW * OH)) % OC; int b = idx / (OW * OH * OC);
  float acc = 0.f;
  const float* ib = in + (size_t)b * IC * IH * IW;
  const float* wb = wgt + (size_t)oc * IC * 9;
  for (int ic = 0; ic < IC; ++ic) {
    const float* ip = ib + ic * IH * IW;
    const float* wp = wb + ic * 9;
#pragma unroll
    for (int ky = 0; ky < 3; ++ky) {
      int ih = oh * 2 + ky - 1;
      if (ih < 0 || ih >= IH) continue;
#pragma unroll
      for (int kx = 0; kx < 3; ++kx) {
        int iw = ow * 2 + kx - 1;
        if (iw < 0 || iw >= IW) continue;
        acc += ip[ih * IW + iw] * wp[ky * 3 + kx];
      }
    }
  }
  out[idx] = acc;  // no relu on conv-c
}

// ---------------- spatial mean ----------------
__global__ void mean_hw_kernel(const float* __restrict__ in, float* __restrict__ out, int n, int hw) {
  int idx = blockIdx.x * blockDim.x + threadIdx.x;
  if (idx >= n) return;
  const float* p = in + (size_t)idx * hw;
  float s = 0.f;
  for (int i = 0; i < hw; ++i) s += p[i];
  out[idx] = s / hw;
}

// ---------------- materialize per-batch adaptive weights ----------------
__global__ void wx_mat_kernel(const float* __restrict__ fv, const float* __restrict__ ww,
                              const float* __restrict__ wb, float* __restrict__ wx,
                              int Cn, int KK) {
  int idx = blockIdx.x * blockDim.x + threadIdx.x;
  if (idx >= B * Cn * KK) return;
  int kk = idx % KK; int i = (idx / KK) % Cn; int b = idx / (KK * Cn);
  wx[idx] = fv[b * Cn + i] * ww[(size_t)i * KK + kk] + wb[(size_t)i * KK + kk];
}

// ---------------- adaptive 3x3 pad-1 stride-1 conv, per-(b,oc) weight row in LDS ----------------
__global__ void adaptive_conv_kernel(const float* __restrict__ feat, const float* __restrict__ wx,
                                     float* __restrict__ out) {
  constexpr int NT = (H * W) / 256;  // 20
  int blk = blockIdx.x;
  int tile = blk % NT; int i = (blk / NT) % CW; int b = blk / (NT * CW);
  __shared__ float lw[CW * 9];
  for (int t = threadIdx.x; t < CW * 9; t += 256) lw[t] = wx[((size_t)(b * CW + i)) * CW * 9 + t];
  __syncthreads();
  int p = tile * 256 + threadIdx.x;
  int h = p / W, w = p % W;
  float acc = 0.f;
  const float* fb = feat + (size_t)b * CW * H * W;
  for (int j = 0; j < CW; ++j) {
    const float* ip = fb + j * H * W;
    const float* wp = lw + j * 9;
#pragma unroll
    for (int ky = 0; ky < 3; ++ky) {
      int ih = h + ky - 1;
      if (ih < 0 || ih >= H) continue;
#pragma unroll
      for (int kx = 0; kx < 3; ++kx) {
        int iw = w + kx - 1;
        if (iw < 0 || iw >= W) continue;
        acc += ip[ih * W + iw] * wp[ky * 3 + kx];
      }
    }
  }
  out[((size_t)(b * CW + i) * H + h) * W + w] = fmaxf(acc, 0.f);
}

// ---------------- final: out = fv2*wxf_w + wxf_b ----------------
__global__ void final_kernel(const float* __restrict__ fv, const float* __restrict__ ww,
                             const float* __restrict__ wb, float* __restrict__ out) {
  int idx = blockIdx.x * blockDim.x + threadIdx.x;
  if (idx >= B * 64 * 576) return;
  int kk = idx % 576; int i = (idx / 576) % 64; int b = idx / (576 * 64);
  out[idx] = fv[b * 64 + i] * ww[i * 576 + kk] + wb[i * 576 + kk];
}

extern "C" void kernel_launch(void* const* d_in, const int* in_sizes, int n_in,
                              void* d_out, int out_size, void* d_ws, size_t ws_size,
                              hipStream_t stream) {
  const float* x0   = (const float*)d_in[0];
  const float* y0   = (const float*)d_in[1];
  const float* x    = (const float*)d_in[2];
  const float* y    = (const float*)d_in[3];
  const float* w1a  = (const float*)d_in[4];
  const float* w1b  = (const float*)d_in[5];
  const float* w1c  = (const float*)d_in[6];
  const float* w2a  = (const float*)d_in[7];
  const float* w2b  = (const float*)d_in[8];
  const float* w2c  = (const float*)d_in[9];
  const float* wx_w = (const float*)d_in[10];
  const float* wx_b = (const float*)d_in[11];
  const float* wxf_w= (const float*)d_in[12];
  const float* wxf_b= (const float*)d_in[13];
  float* out = (float*)d_out;

  // workspace layout (floats)
  float* ws = (float*)d_ws;
  size_t o_xp   = 0;
  size_t o_yp   = o_xp   + (size_t)B * C * H * W;        // 2,621,440
  size_t o_f1   = o_yp   + (size_t)B * C * H * W;
  size_t o_f2   = o_f1   + (size_t)B * CW * H * W;       // 7,249,920
  size_t o_ha   = o_f2   + (size_t)B * CW * H * W;
  size_t o_hb   = o_ha   + (size_t)B * 64 * 32 * 40;     // 655,360
  size_t o_hc   = o_hb   + (size_t)B * 64 * 16 * 20;     // 163,840
  size_t o_fv1  = o_hc   + (size_t)B * CW * 8 * 10;      // 113,280
  size_t o_fv2  = o_fv1  + (size_t)B * CW;
  size_t o_wx   = o_fv2  + (size_t)B * 64;
  size_t total  = o_wx   + (size_t)B * CW * CW * 9;      // 2,255,688
  if (ws_size < total * sizeof(float)) return;  // fail loudly via validation

  float* xp   = ws + o_xp;
  float* yp   = ws + o_yp;
  float* f1   = ws + o_f1;
  float* f2   = ws + o_f2;
  float* ha   = ws + o_ha;
  float* hb   = ws + o_hb;
  float* hc   = ws + o_hc;
  float* fv1  = ws + o_fv1;
  float* fv2  = ws + o_fv2;
  float* wx   = ws + o_wx;

  const int TB = 256;
  int n_pool = B * C * H * W;
  pool2_kernel<<<(n_pool + TB - 1) / TB, TB, 0, stream>>>(x0, xp, n_pool);
  pool2_kernel<<<(n_pool + TB - 1) / TB, TB, 0, stream>>>(y0, yp, n_pool);

  int n_feat = B * CW * H * W;
  corr_concat_kernel<<<(n_feat + TB - 1) / TB, TB, 0, stream>>>(xp, yp, x, y, f1);

  // ---- branch 1 ----
  {
    int grid = B * 64 * ((32 * 40 + 255) / 256);
    conv5_s2_kernel<CW, 64, 80, 32, 40, true><<<grid, TB, CW * 25 * sizeof(float), stream>>>(f1, w1a, ha, 64);
  }
  {
    int grid = B * 64 * ((16 * 20 + 255) / 256);
    conv5_s2_kernel<64, 32, 40, 16, 20, true><<<grid, TB, 64 * 25 * sizeof(float), stream>>>(ha, w1b, hb, 64);
  }
  {
    int n = B * CW * 8 * 10;
    conv3_s2_kernel<64, 16, 20, 8, 10><<<(n + TB - 1) / TB, TB, 0, stream>>>(hb, w1c, hc, CW);
  }
  mean_hw_kernel<<<(B * CW + TB - 1) / TB, TB, 0, stream>>>(hc, fv1, B * CW, 80);

  // ---- adaptive conv ----
  {
    int n = B * CW * CW * 9;
    wx_mat_kernel<<<(n + TB - 1) / TB, TB, 0, stream>>>(fv1, wx_w, wx_b, wx, CW, CW * 9);
  }
  adaptive_conv_kernel<<<B * CW * ((H * W) / 256), TB, 0, stream>>>(f1, wx, f2);

  // ---- branch 2 ----
  {
    int grid = B * 64 * ((32 * 40 + 255) / 256);
    conv5_s2_kernel<CW, 64, 80, 32, 40, true><<<grid, TB, CW * 25 * sizeof(float), stream>>>(f2, w2a, ha, 64);
  }
  {
    int grid = B * 64 * ((16 * 20 + 255) / 256);
    conv5_s2_kernel<64, 32, 40, 16, 20, true><<<grid, TB, 64 * 25 * sizeof(float), stream>>>(ha, w2b, hb, 64);
  }
  {
    int n = B * 64 * 8 * 10;
    conv3_s2_kernel<64, 16, 20, 8, 10><<<(n + TB - 1) / TB, TB, 0, stream>>>(hb, w2c, hc, 64);
  }
  mean_hw_kernel<<<(B * 64 + TB - 1) / TB, TB, 0, stream>>>(hc, fv2, B * 64, 80);

  // ---- final output ----
  final_kernel<<<(B * 64 * 576 + TB - 1) / TB, TB, 0, stream>>>(fv2, wxf_w, wxf_b, out);
}

// Round 2
// 1381.514 us; speedup vs baseline: 5.8300x; 5.8300x over previous
//
#include <hip/hip_runtime.h>

typedef unsigned short u16;
typedef __attribute__((ext_vector_type(8))) short bf16x8;
typedef __attribute__((ext_vector_type(4))) float f32x4;

static constexpr int B  = 8;
static constexpr int C  = 64;
static constexpr int CW = 177;
static constexpr int H  = 64, W  = 80;
static constexpr int HP = 68, WP = 84, KC = 192;          // padded NHWC dims
static constexpr int PB = HP * WP * KC;                   // per-batch elems

__device__ __forceinline__ u16 f2b(float f) {
  union { float f; unsigned u; } v; v.f = f;
  unsigned u = v.u;
  return (u16)((u + 0x7FFF + ((u >> 16) & 1)) >> 16);
}

// ---------------- zero-fill bf16 buffer (16B per thread) ----------------
__global__ void zfill8(u16* __restrict__ p, int n8) {
  int i = blockIdx.x * blockDim.x + threadIdx.x;
  if (i < n8) { bf16x8 z = 0; ((bf16x8*)p)[i] = z; }
}

// ---------------- pool 2x2 mean -> NHWC fp32 ----------------
__global__ void pool2_nhwc(const float* __restrict__ in, float* __restrict__ out) {
  int idx = blockIdx.x * blockDim.x + threadIdx.x;
  if (idx >= B * C * H * W) return;
  int w = idx % W; int h = (idx / W) % H; int c = (idx / (W * H)) % C; int b = idx / (W * H * C);
  const float* p = in + ((size_t)(b * C + c) * 128 + 2 * h) * 160 + 2 * w;
  float v = 0.25f * (p[0] + p[1] + p[160] + p[161]);
  out[((size_t)(b * H + h) * W + w) * C + c] = v;
}

// ---------------- corr (49 offsets) -> featP channels 0..48 (bf16) ----------------
__global__ void corr_fill(const float* __restrict__ xpT, const float* __restrict__ ypT,
                          u16* __restrict__ featP) {
  int idx = blockIdx.x * blockDim.x + threadIdx.x;
  if (idx >= B * H * W * 49) return;
  int o = idx % 49; int p = idx / 49;
  int w = p % W; int h = (p / W) % H; int b = p / (W * H);
  int dy = (o / 7) * 2 - 6, dx = (o % 7) * 2 - 6;
  int hh = h + dy, ww = w + dx;
  float s = 0.f;
  if (hh >= 0 && hh < H && ww >= 0 && ww < W) {
    const float4* xv = (const float4*)(xpT + ((size_t)(b * H + h) * W + w) * C);
    const float4* yv = (const float4*)(ypT + ((size_t)(b * H + hh) * W + ww) * C);
#pragma unroll
    for (int i = 0; i < 16; ++i) {
      float4 a = xv[i], q = yv[i];
      s += a.x * q.x + a.y * q.y + a.z * q.z + a.w * q.w;
    }
  }
  s *= (1.0f / 64.0f);
  featP[((size_t)(b * HP + h + 2) * WP + (w + 2)) * KC + o] = f2b(s);
}

// ---------------- copy x,y -> featP channels 49..176 (bf16) ----------------
__global__ void copyxy(const float* __restrict__ x, const float* __restrict__ y,
                       u16* __restrict__ featP) {
  int idx = blockIdx.x * blockDim.x + threadIdx.x;
  if (idx >= B * 128 * H * W) return;
  int pix = idx % (H * W); int c2 = (idx / (H * W)) % 128; int b = idx / (H * W * 128);
  int h = pix / W, w = pix % W;
  float v = (c2 < 64) ? x[((size_t)(b * C + c2) * H + h) * W + w]
                      : y[((size_t)(b * C + (c2 - 64)) * H + h) * W + w];
  featP[((size_t)(b * HP + h + 2) * WP + (w + 2)) * KC + 49 + c2] = f2b(v);
}

// ---------------- pack adaptive weights: Aad[kk][r][j], r=2i(+1)->wx_w/wx_b ----------------
__global__ void pack_Aad(const float* __restrict__ ww, const float* __restrict__ wb,
                         u16* __restrict__ Aad) {
  int idx = blockIdx.x * blockDim.x + threadIdx.x;
  if (idx >= 9 * 384 * 192) return;
  int j = idx % 192; int r = (idx / 192) % 384; int kk = idx / (192 * 384);
  int i = r >> 1;
  float v = 0.f;
  if (j < CW && i < CW) {
    const float* src = (r & 1) ? wb : ww;
    v = src[(size_t)i * (CW * 9) + j * 9 + kk];
  }
  Aad[idx] = f2b(v);
}

// ---------------- pack 5x5 conv weights: A5[kk][i][j] ----------------
__global__ void pack_A5(const float* __restrict__ w, u16* __restrict__ A5) {
  int idx = blockIdx.x * blockDim.x + threadIdx.x;
  if (idx >= 25 * 64 * 192) return;
  int j = idx % 192; int i = (idx / 192) % 64; int kk = idx / (192 * 64);
  int ky = kk / 5, kx = kk % 5;
  float v = (j < CW) ? w[(((size_t)i * CW + j) * 5 + ky) * 5 + kx] : 0.f;
  A5[idx] = f2b(v);
}

// ---------------- MFMA implicit-GEMM conv over padded NHWC bf16 ----------------
// A: [taps][M][192] bf16, featP: [B][68][84][192] bf16.
// ADEPI: rows pair (2i=W,2i+1=B) -> relu(fv*W+B) -> featP2 bf16.  else: NCHW fp32 + relu.
template<int TY, int TX, int S, int OH, int OW, int M, int BM, int BN, int POFF, bool ADEPI>
__global__ __launch_bounds__(256) void gemm_conv(
    const u16* __restrict__ A, const u16* __restrict__ featP,
    float* __restrict__ outF, u16* __restrict__ outP,
    const float* __restrict__ fv, int MT, int NT) {
  constexpr int WM = BM / 2, WN = BN / 2, FM = WM / 16, FN = WN / 16;
  int bid = blockIdx.x;
  int mt = bid % MT; int rest = bid / MT; int nt = rest % NT; int b = rest / NT;
  int lane = threadIdx.x & 63; int wv = threadIdx.x >> 6;
  int wm = wv >> 1, wn = wv & 1;
  int l15 = lane & 15, kq = lane >> 4;

  f32x4 acc[FM][FN];
#pragma unroll
  for (int i = 0; i < FM; ++i)
#pragma unroll
    for (int j = 0; j < FN; ++j) acc[i][j] = (f32x4){0.f, 0.f, 0.f, 0.f};

  const u16* Abase = A + (size_t)(mt * BM + wm * WM + l15) * KC + kq * 8;
  const u16* fb = featP + (size_t)b * PB + kq * 8;

  int ohh[FN], oww[FN];
#pragma unroll
  for (int fn = 0; fn < FN; ++fn) {
    int p = nt * BN + wn * WN + fn * 16 + l15;
    ohh[fn] = p / OW; oww[fn] = p % OW;
  }

  for (int ty = 0; ty < TY; ++ty)
    for (int tx = 0; tx < TX; ++tx) {
      const u16* At = Abase + (size_t)((ty * TX + tx) * M) * KC;
      const u16* Bt[FN];
#pragma unroll
      for (int fn = 0; fn < FN; ++fn) {
        int hi = ohh[fn] * S + ty + POFF;
        int wi = oww[fn] * S + tx + POFF;
        Bt[fn] = fb + (size_t)(hi * WP + wi) * KC;
      }
#pragma unroll
      for (int kc = 0; kc < 6; ++kc) {
        bf16x8 av[FM], bv[FN];
#pragma unroll
        for (int fm = 0; fm < FM; ++fm)
          av[fm] = *(const bf16x8*)(At + fm * 16 * KC + kc * 32);
#pragma unroll
        for (int fn = 0; fn < FN; ++fn)
          bv[fn] = *(const bf16x8*)(Bt[fn] + kc * 32);
#pragma unroll
        for (int fm = 0; fm < FM; ++fm)
#pragma unroll
          for (int fn = 0; fn < FN; ++fn)
            acc[fm][fn] = __builtin_amdgcn_mfma_f32_16x16x32_bf16(av[fm], bv[fn], acc[fm][fn], 0, 0, 0);
      }
    }

  if constexpr (ADEPI) {
#pragma unroll
    for (int fm = 0; fm < FM; ++fm) {
      int rbase = mt * BM + wm * WM + fm * 16 + kq * 4;
      int i0 = rbase >> 1;
#pragma unroll
      for (int fn = 0; fn < FN; ++fn) {
        u16* dst = outP + ((size_t)(b * HP + ohh[fn] + 2) * WP + (oww[fn] + 2)) * KC;
#pragma unroll
        for (int pr = 0; pr < 2; ++pr) {
          int i = i0 + pr;
          if (i < CW) {
            float v = fv[b * CW + i] * acc[fm][fn][2 * pr] + acc[fm][fn][2 * pr + 1];
            dst[i] = f2b(fmaxf(v, 0.f));
          }
        }
      }
    }
  } else {
#pragma unroll
    for (int fm = 0; fm < FM; ++fm) {
      int oc0 = mt * BM + wm * WM + fm * 16 + kq * 4;
#pragma unroll
      for (int fn = 0; fn < FN; ++fn) {
#pragma unroll
        for (int r = 0; r < 4; ++r) {
          float v = fmaxf(acc[fm][fn][r], 0.f);
          outF[(((size_t)b * M + oc0 + r) * OH + ohh[fn]) * OW + oww[fn]] = v;
        }
      }
    }
  }
}

// ---------------- naive 5x5 s2 conv (small, 64ch) ----------------
template<int IC, int IH, int IW, int OH, int OW, bool RELU>
__global__ void conv5_s2_kernel(const float* __restrict__ in, const float* __restrict__ wgt,
                                float* __restrict__ out, int OC) {
  constexpr int NT = (OH * OW + 255) / 256;
  int blk = blockIdx.x;
  int tile = blk % NT; int oc = (blk / NT) % OC; int b = blk / (NT * OC);
  extern __shared__ float lw[];
  for (int t = threadIdx.x; t < IC * 25; t += blockDim.x) lw[t] = wgt[(size_t)oc * IC * 25 + t];
  __syncthreads();
  int p = tile * 256 + threadIdx.x;
  if (p >= OH * OW) return;
  int oh = p / OW, ow = p % OW;
  float acc = 0.f;
  const float* ib = in + (size_t)b * IC * IH * IW;
  for (int ic = 0; ic < IC; ++ic) {
    const float* ip = ib + ic * IH * IW;
    const float* wp = lw + ic * 25;
#pragma unroll
    for (int ky = 0; ky < 5; ++ky) {
      int ih = oh * 2 + ky - 2;
      if (ih < 0 || ih >= IH) continue;
#pragma unroll
      for (int kx = 0; kx < 5; ++kx) {
        int iw = ow * 2 + kx - 2;
        if (iw < 0 || iw >= IW) continue;
        acc += ip[ih * IW + iw] * wp[ky * 5 + kx];
      }
    }
  }
  if (RELU) acc = fmaxf(acc, 0.f);
  out[((size_t)(b * OC + oc) * OH + oh) * OW + ow] = acc;
}

// ---------------- naive 3x3 s2 conv ----------------
template<int IC, int IH, int IW, int OH, int OW>
__global__ void conv3_s2_kernel(const float* __restrict__ in, const float* __restrict__ wgt,
                                float* __restrict__ out, int OC) {
  int idx = blockIdx.x * blockDim.x + threadIdx.x;
  if (idx >= B * OC * OH * OW) return;
  int ow = idx % OW; int oh = (idx / OW) % OH; int oc = (idx / (OW * OH)) % OC; int b = idx / (OW * OH * OC);
  float acc = 0.f;
  const float* ib = in + (size_t)b * IC * IH * IW;
  const float* wb = wgt + (size_t)oc * IC * 9;
  for (int ic = 0; ic < IC; ++ic) {
    const float* ip = ib + ic * IH * IW;
    const float* wp = wb + ic * 9;
#pragma unroll
    for (int ky = 0; ky < 3; ++ky) {
      int ih = oh * 2 + ky - 1;
      if (ih < 0 || ih >= IH) continue;
#pragma unroll
      for (int kx = 0; kx < 3; ++kx) {
        int iw = ow * 2 + kx - 1;
        if (iw < 0 || iw >= IW) continue;
        acc += ip[ih * IW + iw] * wp[ky * 3 + kx];
      }
    }
  }
  out[idx] = acc;
}

// ---------------- spatial mean ----------------
__global__ void mean_hw_kernel(const float* __restrict__ in, float* __restrict__ out, int n, int hw) {
  int idx = blockIdx.x * blockDim.x + threadIdx.x;
  if (idx >= n) return;
  const float* p = in + (size_t)idx * hw;
  float s = 0.f;
  for (int i = 0; i < hw; ++i) s += p[i];
  out[idx] = s / hw;
}

// ---------------- final: out = fv2*wxf_w + wxf_b ----------------
__global__ void final_kernel(const float* __restrict__ fv, const float* __restrict__ ww,
                             const float* __restrict__ wb, float* __restrict__ out) {
  int idx = blockIdx.x * blockDim.x + threadIdx.x;
  if (idx >= B * 64 * 576) return;
  int kk = idx % 576; int i = (idx / 576) % 64; int b = idx / (576 * 64);
  out[idx] = fv[b * 64 + i] * ww[i * 576 + kk] + wb[i * 576 + kk];
}

extern "C" void kernel_launch(void* const* d_in, const int* in_sizes, int n_in,
                              void* d_out, int out_size, void* d_ws, size_t ws_size,
                              hipStream_t stream) {
  const float* x0    = (const float*)d_in[0];
  const float* y0    = (const float*)d_in[1];
  const float* x     = (const float*)d_in[2];
  const float* y     = (const float*)d_in[3];
  const float* w1a   = (const float*)d_in[4];
  const float* w1b   = (const float*)d_in[5];
  const float* w1c   = (const float*)d_in[6];
  const float* w2a   = (const float*)d_in[7];
  const float* w2b   = (const float*)d_in[8];
  const float* w2c   = (const float*)d_in[9];
  const float* wx_w  = (const float*)d_in[10];
  const float* wx_b  = (const float*)d_in[11];
  const float* wxf_w = (const float*)d_in[12];
  const float* wxf_b = (const float*)d_in[13];
  float* out = (float*)d_out;

  char* base = (char*)d_ws;
  size_t off = 0;
  auto take = [&](size_t bytes) -> char* {
    char* p = base + off; off += (bytes + 255) & ~(size_t)255; return p;
  };
  u16*   featP1 = (u16*)take((size_t)B * PB * 2);         // 17.55 MB
  float* xpT    = (float*)take((size_t)B * H * W * C * 4); // 10.49 MB (aliased by featP2)
  float* ypT    = (float*)take((size_t)B * H * W * C * 4); // 10.49 MB (featP2 tail)
  u16*   featP2 = (u16*)(void*)xpT;                        // reuse: 21 MB >= 17.55 MB
  u16*   Aad    = (u16*)take((size_t)9 * 384 * 192 * 2);
  u16*   A5a    = (u16*)take((size_t)25 * 64 * 192 * 2);
  u16*   A5b    = (u16*)take((size_t)25 * 64 * 192 * 2);
  float* ha     = (float*)take((size_t)B * 64 * 32 * 40 * 4);
  float* hb     = (float*)take((size_t)B * 64 * 16 * 20 * 4);
  float* hc     = (float*)take((size_t)B * CW * 80 * 4);
  float* fv1    = (float*)take((size_t)B * CW * 4);
  float* fv2    = (float*)take((size_t)B * 64 * 4);
  if (off > ws_size) return;

  const int TB = 256;
  int nfull8 = (B * PB) / 8;

  // featP1 zero (halo + pad channels)
  zfill8<<<(nfull8 + TB - 1) / TB, TB, 0, stream>>>(featP1, nfull8);
  // pools (NHWC)
  {
    int n = B * C * H * W;
    pool2_nhwc<<<(n + TB - 1) / TB, TB, 0, stream>>>(x0, xpT);
    pool2_nhwc<<<(n + TB - 1) / TB, TB, 0, stream>>>(y0, ypT);
  }
  // corr + concat into featP1
  {
    int n = B * H * W * 49;
    corr_fill<<<(n + TB - 1) / TB, TB, 0, stream>>>(xpT, ypT, featP1);
    int n2 = B * 128 * H * W;
    copyxy<<<(n2 + TB - 1) / TB, TB, 0, stream>>>(x, y, featP1);
  }
  // featP2 zero (xpT/ypT no longer needed)
  zfill8<<<(nfull8 + TB - 1) / TB, TB, 0, stream>>>(featP2, nfull8);
  // weight packs
  pack_Aad<<<(9 * 384 * 192 + TB - 1) / TB, TB, 0, stream>>>(wx_w, wx_b, Aad);
  pack_A5<<<(25 * 64 * 192 + TB - 1) / TB, TB, 0, stream>>>(w1a, A5a);
  pack_A5<<<(25 * 64 * 192 + TB - 1) / TB, TB, 0, stream>>>(w2a, A5b);

  // ---- branch 1 ----
  gemm_conv<5, 5, 2, 32, 40, 64, 64, 64, 0, false>
      <<<1 * 20 * B, TB, 0, stream>>>(A5a, featP1, ha, nullptr, nullptr, 1, 20);
  conv5_s2_kernel<64, 32, 40, 16, 20, true>
      <<<B * 64 * 2, TB, 64 * 25 * sizeof(float), stream>>>(ha, w1b, hb, 64);
  conv3_s2_kernel<64, 16, 20, 8, 10>
      <<<(B * CW * 80 + TB - 1) / TB, TB, 0, stream>>>(hb, w1c, hc, CW);
  mean_hw_kernel<<<(B * CW + TB - 1) / TB, TB, 0, stream>>>(hc, fv1, B * CW, 80);

  // ---- adaptive conv (decomposed, fused epilogue) ----
  gemm_conv<3, 3, 1, 64, 80, 384, 64, 160, 1, true>
      <<<6 * 32 * B, TB, 0, stream>>>(Aad, featP1, nullptr, featP2, fv1, 6, 32);

  // ---- branch 2 ----
  gemm_conv<5, 5, 2, 32, 40, 64, 64, 64, 0, false>
      <<<1 * 20 * B, TB, 0, stream>>>(A5b, featP2, ha, nullptr, nullptr, 1, 20);
  conv5_s2_kernel<64, 32, 40, 16, 20, true>
      <<<B * 64 * 2, TB, 64 * 25 * sizeof(float), stream>>>(ha, w2b, hb, 64);
  conv3_s2_kernel<64, 16, 20, 8, 10>
      <<<(B * 64 * 80 + TB - 1) / TB, TB, 0, stream>>>(hb, w2c, hc, 64);
  mean_hw_kernel<<<(B * 64 + TB - 1) / TB, TB, 0, stream>>>(hc, fv2, B * 64, 80);

  // ---- final output ----
  final_kernel<<<(B * 64 * 576 + TB - 1) / TB, TB, 0, stream>>>(fv2, wxf_w, wxf_b, out);
}

// Round 3
// 630.021 us; speedup vs baseline: 12.7840x; 2.1928x over previous
//
#include <hip/hip_runtime.h>

typedef unsigned short u16;
typedef __attribute__((ext_vector_type(8))) short bf16x8;
typedef __attribute__((ext_vector_type(4))) float f32x4;

static constexpr int B  = 8;
static constexpr int C  = 64;
static constexpr int CW = 177;
static constexpr int H  = 64, W  = 80;
static constexpr int HP = 68, WP = 84, KC = 192;   // feat padded NHWC
static constexpr int PB = HP * WP * KC;
static constexpr int HA = 36, WA = 44;             // conv5a out padded (32x40 + halo2)

__device__ __forceinline__ u16 f2b(float f) {
  union { float f; unsigned u; } v; v.f = f;
  unsigned u = v.u;
  return (u16)((u + 0x7FFF + ((u >> 16) & 1)) >> 16);
}

__global__ void zfill8(u16* __restrict__ p, int n8) {
  int i = blockIdx.x * blockDim.x + threadIdx.x;
  if (i < n8) { bf16x8 z = 0; ((bf16x8*)p)[i] = z; }
}

// ---------------- pool 2x2 mean -> NHWC fp32 ----------------
__global__ void pool2_nhwc(const float* __restrict__ in, float* __restrict__ out) {
  int idx = blockIdx.x * blockDim.x + threadIdx.x;
  if (idx >= B * C * H * W) return;
  int w = idx % W; int h = (idx / W) % H; int c = (idx / (W * H)) % C; int b = idx / (W * H * C);
  const float* p = in + ((size_t)(b * C + c) * 128 + 2 * h) * 160 + 2 * w;
  float v = 0.25f * (p[0] + p[1] + p[160] + p[161]);
  out[((size_t)(b * H + h) * W + w) * C + c] = v;
}

// ---------------- corr -> featP channels 0..48 ----------------
__global__ void corr_fill(const float* __restrict__ xpT, const float* __restrict__ ypT,
                          u16* __restrict__ featP) {
  int idx = blockIdx.x * blockDim.x + threadIdx.x;
  if (idx >= B * H * W * 49) return;
  int o = idx % 49; int p = idx / 49;
  int w = p % W; int h = (p / W) % H; int b = p / (W * H);
  int dy = (o / 7) * 2 - 6, dx = (o % 7) * 2 - 6;
  int hh = h + dy, ww = w + dx;
  float s = 0.f;
  if (hh >= 0 && hh < H && ww >= 0 && ww < W) {
    const float4* xv = (const float4*)(xpT + ((size_t)(b * H + h) * W + w) * C);
    const float4* yv = (const float4*)(ypT + ((size_t)(b * H + hh) * W + ww) * C);
#pragma unroll
    for (int i = 0; i < 16; ++i) {
      float4 a = xv[i], q = yv[i];
      s += a.x * q.x + a.y * q.y + a.z * q.z + a.w * q.w;
    }
  }
  s *= (1.0f / 64.0f);
  featP[((size_t)(b * HP + h + 2) * WP + (w + 2)) * KC + o] = f2b(s);
}

// ---------------- x,y -> featP channels 49..176 ----------------
__global__ void copyxy(const float* __restrict__ x, const float* __restrict__ y,
                       u16* __restrict__ featP) {
  int idx = blockIdx.x * blockDim.x + threadIdx.x;
  if (idx >= B * 128 * H * W) return;
  int pix = idx % (H * W); int c2 = (idx / (H * W)) % 128; int b = idx / (H * W * 128);
  int h = pix / W, w = pix % W;
  float v = (c2 < 64) ? x[((size_t)(b * C + c2) * H + h) * W + w]
                      : y[((size_t)(b * C + (c2 - 64)) * H + h) * W + w];
  featP[((size_t)(b * HP + h + 2) * WP + (w + 2)) * KC + 49 + c2] = f2b(v);
}

// ---------------- pack adaptive weights: Aad[kk][r][j] ----------------
__global__ void pack_Aad(const float* __restrict__ ww, const float* __restrict__ wb,
                         u16* __restrict__ Aad) {
  int idx = blockIdx.x * blockDim.x + threadIdx.x;
  if (idx >= 9 * 384 * 192) return;
  int j = idx % 192; int r = (idx / 192) % 384; int kk = idx / (192 * 384);
  int i = r >> 1;
  float v = 0.f;
  if (j < CW && i < CW) {
    const float* src = (r & 1) ? wb : ww;
    v = src[(size_t)i * (CW * 9) + j * 9 + kk];
  }
  Aad[idx] = f2b(v);
}

// ---------------- pack 5x5 weights: A[kk][i][KCA] ----------------
__global__ void pack_w5(const float* __restrict__ w, u16* __restrict__ A, int KCA, int ICR) {
  int idx = blockIdx.x * blockDim.x + threadIdx.x;
  if (idx >= 25 * 64 * KCA) return;
  int j = idx % KCA; int i = (idx / KCA) % 64; int kk = idx / (KCA * 64);
  int ky = kk / 5, kx = kk % 5;
  float v = (j < ICR) ? w[(((size_t)i * ICR + j) * 5 + ky) * 5 + kx] : 0.f;
  A[idx] = f2b(v);
}

// ---------------- MFMA implicit-GEMM conv over padded NHWC bf16 ----------------
// EPI 0: fp32 NCHW + relu; EPI 1: adaptive pair-combine -> bf16 NHWC padded;
// EPI 2: bf16 NHWC padded + relu.
template<int TY, int TX, int S, int OH, int OW, int M, int BM, int BN, int POFF,
         int KCIN, int HPIN, int WPIN, int HPOUT, int WPOUT, int KCOUT, int EPI>
__global__ __launch_bounds__(256) void gemm_conv(
    const u16* __restrict__ A, const u16* __restrict__ featP,
    float* __restrict__ outF, u16* __restrict__ outP,
    const float* __restrict__ fv, int MT, int NT) {
  constexpr int WM = BM / 2, WN = BN / 2, FM = WM / 16, FN = WN / 16;
  constexpr int NKC = KCIN / 32;
  int bid = blockIdx.x;
  int mt = bid % MT; int rest = bid / MT; int nt = rest % NT; int b = rest / NT;
  int lane = threadIdx.x & 63; int wv = threadIdx.x >> 6;
  int wm = wv >> 1, wn = wv & 1;
  int l15 = lane & 15, kq = lane >> 4;

  f32x4 acc[FM][FN];
#pragma unroll
  for (int i = 0; i < FM; ++i)
#pragma unroll
    for (int j = 0; j < FN; ++j) acc[i][j] = (f32x4){0.f, 0.f, 0.f, 0.f};

  const u16* Abase = A + (size_t)(mt * BM + wm * WM + l15) * KCIN + kq * 8;
  const u16* fb = featP + (size_t)b * (HPIN * WPIN * KCIN) + kq * 8;

  int ohh[FN], oww[FN];
#pragma unroll
  for (int fn = 0; fn < FN; ++fn) {
    int p = nt * BN + wn * WN + fn * 16 + l15;
    ohh[fn] = p / OW; oww[fn] = p % OW;
  }

  for (int ty = 0; ty < TY; ++ty)
    for (int tx = 0; tx < TX; ++tx) {
      const u16* At = Abase + (size_t)((ty * TX + tx) * M) * KCIN;
      const u16* Bt[FN];
#pragma unroll
      for (int fn = 0; fn < FN; ++fn) {
        int hi = ohh[fn] * S + ty + POFF;
        int wi = oww[fn] * S + tx + POFF;
        Bt[fn] = fb + (size_t)(hi * WPIN + wi) * KCIN;
      }
#pragma unroll
      for (int kc = 0; kc < NKC; ++kc) {
        bf16x8 av[FM], bv[FN];
#pragma unroll
        for (int fm = 0; fm < FM; ++fm)
          av[fm] = *(const bf16x8*)(At + fm * 16 * KCIN + kc * 32);
#pragma unroll
        for (int fn = 0; fn < FN; ++fn)
          bv[fn] = *(const bf16x8*)(Bt[fn] + kc * 32);
#pragma unroll
        for (int fm = 0; fm < FM; ++fm)
#pragma unroll
          for (int fn = 0; fn < FN; ++fn)
            acc[fm][fn] = __builtin_amdgcn_mfma_f32_16x16x32_bf16(av[fm], bv[fn], acc[fm][fn], 0, 0, 0);
      }
    }

  if constexpr (EPI == 1) {
#pragma unroll
    for (int fm = 0; fm < FM; ++fm) {
      int rbase = mt * BM + wm * WM + fm * 16 + kq * 4;
      int i0 = rbase >> 1;
#pragma unroll
      for (int fn = 0; fn < FN; ++fn) {
        u16* dst = outP + ((size_t)(b * HPOUT + ohh[fn] + 2) * WPOUT + (oww[fn] + 2)) * KCOUT;
#pragma unroll
        for (int pr = 0; pr < 2; ++pr) {
          int i = i0 + pr;
          if (i < CW) {
            float v = fv[b * CW + i] * acc[fm][fn][2 * pr] + acc[fm][fn][2 * pr + 1];
            dst[i] = f2b(fmaxf(v, 0.f));
          }
        }
      }
    }
  } else if constexpr (EPI == 2) {
#pragma unroll
    for (int fm = 0; fm < FM; ++fm) {
      int oc0 = mt * BM + wm * WM + fm * 16 + kq * 4;
#pragma unroll
      for (int fn = 0; fn < FN; ++fn) {
        u16* dst = outP + ((size_t)(b * HPOUT + ohh[fn] + 2) * WPOUT + (oww[fn] + 2)) * KCOUT + oc0;
#pragma unroll
        for (int r = 0; r < 4; ++r)
          dst[r] = f2b(fmaxf(acc[fm][fn][r], 0.f));
      }
    }
  } else {
#pragma unroll
    for (int fm = 0; fm < FM; ++fm) {
      int oc0 = mt * BM + wm * WM + fm * 16 + kq * 4;
#pragma unroll
      for (int fn = 0; fn < FN; ++fn) {
#pragma unroll
        for (int r = 0; r < 4; ++r) {
          float v = fmaxf(acc[fm][fn][r], 0.f);
          outF[(((size_t)b * M + oc0 + r) * OH + ohh[fn]) * OW + oww[fn]] = v;
        }
      }
    }
  }
}

// ---------------- conv3+mean fold, step 1: 9-bin tap sums of hb ----------------
// S[b][ic][ky*3+kx] = sum over valid (oh,ow) of hb[b,ic,oh*2+ky-1,ow*2+kx-1]
__global__ void tapsum_kernel(const float* __restrict__ hb, float* __restrict__ Sm) {
  int b = blockIdx.x >> 6; int ic = blockIdx.x & 63; int lane = threadIdx.x;
  const float* p = hb + ((size_t)(b * 64 + ic)) * 320;
  float s[9];
#pragma unroll
  for (int t = 0; t < 9; ++t) s[t] = 0.f;
  for (int i = lane; i < 320; i += 64) {
    int ih = i / 20, iw = i % 20;
    float v = p[i];
#pragma unroll
    for (int ky = 0; ky < 3; ++ky) {
      int t2 = ih + 1 - ky;
      if (t2 < 0 || t2 > 14 || (t2 & 1)) continue;
#pragma unroll
      for (int kx = 0; kx < 3; ++kx) {
        int t3 = iw + 1 - kx;
        if (t3 < 0 || t3 > 18 || (t3 & 1)) continue;
        s[ky * 3 + kx] += v;
      }
    }
  }
#pragma unroll
  for (int t = 0; t < 9; ++t)
#pragma unroll
    for (int off = 32; off > 0; off >>= 1) s[t] += __shfl_down(s[t], off);
  if (lane == 0) {
#pragma unroll
    for (int t = 0; t < 9; ++t) Sm[(b * 64 + ic) * 9 + t] = s[t];
  }
}

// ---------------- step 2: fv[b][o] = (1/80) * sum_{ic,t} w3[o,ic,t]*S[b,ic,t] ----------------
__global__ void gemv_fv(const float* __restrict__ w3, const float* __restrict__ Sm,
                        float* __restrict__ fv, int OC) {
  int o = blockIdx.x % OC; int b = blockIdx.x / OC; int lane = threadIdx.x;
  const float* wp = w3 + ((size_t)o * 64 + lane) * 9;
  const float* sp = Sm + ((size_t)b * 64 + lane) * 9;
  float acc = 0.f;
#pragma unroll
  for (int t = 0; t < 9; ++t) acc += wp[t] * sp[t];
#pragma unroll
  for (int off = 32; off > 0; off >>= 1) acc += __shfl_down(acc, off);
  if (lane == 0) fv[b * OC + o] = acc * (1.0f / 80.0f);
}

// ---------------- final: out = fv2*wxf_w + wxf_b ----------------
__global__ void final_kernel(const float* __restrict__ fv, const float* __restrict__ ww,
                             const float* __restrict__ wb, float* __restrict__ out) {
  int idx = blockIdx.x * blockDim.x + threadIdx.x;
  if (idx >= B * 64 * 576) return;
  int kk = idx % 576; int i = (idx / 576) % 64; int b = idx / (576 * 64);
  out[idx] = fv[b * 64 + i] * ww[i * 576 + kk] + wb[i * 576 + kk];
}

extern "C" void kernel_launch(void* const* d_in, const int* in_sizes, int n_in,
                              void* d_out, int out_size, void* d_ws, size_t ws_size,
                              hipStream_t stream) {
  const float* x0    = (const float*)d_in[0];
  const float* y0    = (const float*)d_in[1];
  const float* x     = (const float*)d_in[2];
  const float* y     = (const float*)d_in[3];
  const float* w1a   = (const float*)d_in[4];
  const float* w1b   = (const float*)d_in[5];
  const float* w1c   = (const float*)d_in[6];
  const float* w2a   = (const float*)d_in[7];
  const float* w2b   = (const float*)d_in[8];
  const float* w2c   = (const float*)d_in[9];
  const float* wx_w  = (const float*)d_in[10];
  const float* wx_b  = (const float*)d_in[11];
  const float* wxf_w = (const float*)d_in[12];
  const float* wxf_b = (const float*)d_in[13];
  float* out = (float*)d_out;

  char* base = (char*)d_ws;
  size_t off = 0;
  auto take = [&](size_t bytes) -> char* {
    char* p = base + off; off += (bytes + 255) & ~(size_t)255; return p;
  };
  u16*   featP1 = (u16*)take((size_t)B * PB * 2);
  float* xpT    = (float*)take((size_t)B * H * W * C * 4);
  float* ypT    = (float*)take((size_t)B * H * W * C * 4);
  u16*   featP2 = (u16*)(void*)xpT;                 // alias: 21 MB >= 17.55 MB
  u16*   Aad    = (u16*)take((size_t)9 * 384 * 192 * 2);
  u16*   A5a    = (u16*)take((size_t)25 * 64 * 192 * 2);
  u16*   A5b    = (u16*)take((size_t)25 * 64 * 192 * 2);
  u16*   A5b1   = (u16*)take((size_t)25 * 64 * 64 * 2);
  u16*   A5b2   = (u16*)take((size_t)25 * 64 * 64 * 2);
  u16*   haP    = (u16*)take((size_t)B * HA * WA * 64 * 2);
  float* hb     = (float*)take((size_t)B * 64 * 320 * 4);
  float* Sm     = (float*)take((size_t)B * 64 * 9 * 4);
  float* fv1    = (float*)take((size_t)B * CW * 4);
  float* fv2    = (float*)take((size_t)B * 64 * 4);
  if (off > ws_size) return;

  const int TB = 256;
  int nfull8 = (B * PB) / 8;
  int nha8 = (B * HA * WA * 64) / 8;

  zfill8<<<(nfull8 + TB - 1) / TB, TB, 0, stream>>>(featP1, nfull8);
  zfill8<<<(nha8 + TB - 1) / TB, TB, 0, stream>>>(haP, nha8);
  {
    int n = B * C * H * W;
    pool2_nhwc<<<(n + TB - 1) / TB, TB, 0, stream>>>(x0, xpT);
    pool2_nhwc<<<(n + TB - 1) / TB, TB, 0, stream>>>(y0, ypT);
  }
  {
    int n = B * H * W * 49;
    corr_fill<<<(n + TB - 1) / TB, TB, 0, stream>>>(xpT, ypT, featP1);
    int n2 = B * 128 * H * W;
    copyxy<<<(n2 + TB - 1) / TB, TB, 0, stream>>>(x, y, featP1);
  }
  zfill8<<<(nfull8 + TB - 1) / TB, TB, 0, stream>>>(featP2, nfull8);
  pack_Aad<<<(9 * 384 * 192 + TB - 1) / TB, TB, 0, stream>>>(wx_w, wx_b, Aad);
  pack_w5<<<(25 * 64 * 192 + TB - 1) / TB, TB, 0, stream>>>(w1a, A5a, 192, CW);
  pack_w5<<<(25 * 64 * 192 + TB - 1) / TB, TB, 0, stream>>>(w2a, A5b, 192, CW);
  pack_w5<<<(25 * 64 * 64 + TB - 1) / TB, TB, 0, stream>>>(w1b, A5b1, 64, 64);
  pack_w5<<<(25 * 64 * 64 + TB - 1) / TB, TB, 0, stream>>>(w2b, A5b2, 64, 64);

  // ---- branch 1 ----
  gemm_conv<5, 5, 2, 32, 40, 64, 64, 64, 0, 192, 68, 84, HA, WA, 64, 2>
      <<<20 * B, TB, 0, stream>>>(A5a, featP1, nullptr, haP, nullptr, 1, 20);
  gemm_conv<5, 5, 2, 16, 20, 64, 64, 64, 0, 64, HA, WA, 0, 0, 0, 0>
      <<<5 * B, TB, 0, stream>>>(A5b1, haP, hb, nullptr, nullptr, 1, 5);
  tapsum_kernel<<<B * 64, 64, 0, stream>>>(hb, Sm);
  gemv_fv<<<B * CW, 64, 0, stream>>>(w1c, Sm, fv1, CW);

  // ---- adaptive conv ----
  gemm_conv<3, 3, 1, 64, 80, 384, 64, 160, 1, 192, 68, 84, 68, 84, 192, 1>
      <<<6 * 32 * B, TB, 0, stream>>>(Aad, featP1, nullptr, featP2, fv1, 6, 32);

  // ---- branch 2 ----
  gemm_conv<5, 5, 2, 32, 40, 64, 64, 64, 0, 192, 68, 84, HA, WA, 64, 2>
      <<<20 * B, TB, 0, stream>>>(A5b, featP2, nullptr, haP, nullptr, 1, 20);
  gemm_conv<5, 5, 2, 16, 20, 64, 64, 64, 0, 64, HA, WA, 0, 0, 0, 0>
      <<<5 * B, TB, 0, stream>>>(A5b2, haP, hb, nullptr, nullptr, 1, 5);
  tapsum_kernel<<<B * 64, 64, 0, stream>>>(hb, Sm);
  gemv_fv<<<B * 64, 64, 0, stream>>>(w2c, Sm, fv2, 64);

  // ---- final output ----
  final_kernel<<<(B * 64 * 576 + TB - 1) / TB, TB, 0, stream>>>(fv2, wxf_w, wxf_b, out);
}

// Round 4
// 473.142 us; speedup vs baseline: 17.0228x; 1.3316x over previous
//
#include <hip/hip_runtime.h>

typedef unsigned short u16;
typedef __attribute__((ext_vector_type(8))) short bf16x8;
typedef __attribute__((ext_vector_type(4))) float f32x4;

static constexpr int B  = 8;
static constexpr int C  = 64;
static constexpr int CW = 177;
static constexpr int H  = 64, W  = 80;
static constexpr int HP = 68, WP = 84, KC = 192;   // feat padded NHWC
static constexpr int PB = HP * WP * KC;
static constexpr int HA = 36, WA = 44;             // conv5a out padded (32x40 + halo2)

__device__ __forceinline__ u16 f2b(float f) {
  union { float f; unsigned u; } v; v.f = f;
  unsigned u = v.u;
  return (u16)((u + 0x7FFF + ((u >> 16) & 1)) >> 16);
}

__global__ void zfill8(u16* __restrict__ p, int n8) {
  int i = blockIdx.x * blockDim.x + threadIdx.x;
  if (i < n8) { bf16x8 z = 0; ((bf16x8*)p)[i] = z; }
}

// ---------------- pool 2x2 mean -> NHWC fp32 ----------------
__global__ void pool2_nhwc(const float* __restrict__ in, float* __restrict__ out) {
  int idx = blockIdx.x * blockDim.x + threadIdx.x;
  if (idx >= B * C * H * W) return;
  int w = idx % W; int h = (idx / W) % H; int c = (idx / (W * H)) % C; int b = idx / (W * H * C);
  const float* p = in + ((size_t)(b * C + c) * 128 + 2 * h) * 160 + 2 * w;
  float v = 0.25f * (p[0] + p[1] + p[160] + p[161]);
  out[((size_t)(b * H + h) * W + w) * C + c] = v;
}

// ---------------- corr -> featP channels 0..48 ----------------
__global__ void corr_fill(const float* __restrict__ xpT, const float* __restrict__ ypT,
                          u16* __restrict__ featP) {
  int idx = blockIdx.x * blockDim.x + threadIdx.x;
  if (idx >= B * H * W * 49) return;
  int o = idx % 49; int p = idx / 49;
  int w = p % W; int h = (p / W) % H; int b = p / (W * H);
  int dy = (o / 7) * 2 - 6, dx = (o % 7) * 2 - 6;
  int hh = h + dy, ww = w + dx;
  float s = 0.f;
  if (hh >= 0 && hh < H && ww >= 0 && ww < W) {
    const float4* xv = (const float4*)(xpT + ((size_t)(b * H + h) * W + w) * C);
    const float4* yv = (const float4*)(ypT + ((size_t)(b * H + hh) * W + ww) * C);
#pragma unroll
    for (int i = 0; i < 16; ++i) {
      float4 a = xv[i], q = yv[i];
      s += a.x * q.x + a.y * q.y + a.z * q.z + a.w * q.w;
    }
  }
  s *= (1.0f / 64.0f);
  featP[((size_t)(b * HP + h + 2) * WP + (w + 2)) * KC + o] = f2b(s);
}

// ---------------- x,y -> featP channels 49..176 ----------------
__global__ void copyxy(const float* __restrict__ x, const float* __restrict__ y,
                       u16* __restrict__ featP) {
  int idx = blockIdx.x * blockDim.x + threadIdx.x;
  if (idx >= B * 128 * H * W) return;
  int pix = idx % (H * W); int c2 = (idx / (H * W)) % 128; int b = idx / (H * W * 128);
  int h = pix / W, w = pix % W;
  float v = (c2 < 64) ? x[((size_t)(b * C + c2) * H + h) * W + w]
                      : y[((size_t)(b * C + (c2 - 64)) * H + h) * W + w];
  featP[((size_t)(b * HP + h + 2) * WP + (w + 2)) * KC + 49 + c2] = f2b(v);
}

// ---------------- pack adaptive weights: Aad[kk][r][j] ----------------
__global__ void pack_Aad(const float* __restrict__ ww, const float* __restrict__ wb,
                         u16* __restrict__ Aad) {
  int idx = blockIdx.x * blockDim.x + threadIdx.x;
  if (idx >= 9 * 384 * 192) return;
  int j = idx % 192; int r = (idx / 192) % 384; int kk = idx / (192 * 384);
  int i = r >> 1;
  float v = 0.f;
  if (j < CW && i < CW) {
    const float* src = (r & 1) ? wb : ww;
    v = src[(size_t)i * (CW * 9) + j * 9 + kk];
  }
  Aad[idx] = f2b(v);
}

// ---------------- pack 5x5 weights: A[kk][i][KCA] ----------------
__global__ void pack_w5(const float* __restrict__ w, u16* __restrict__ A, int KCA, int ICR) {
  int idx = blockIdx.x * blockDim.x + threadIdx.x;
  if (idx >= 25 * 64 * KCA) return;
  int j = idx % KCA; int i = (idx / KCA) % 64; int kk = idx / (KCA * 64);
  int ky = kk / 5, kx = kk % 5;
  float v = (j < ICR) ? w[(((size_t)i * ICR + j) * 5 + ky) * 5 + kx] : 0.f;
  A[idx] = f2b(v);
}

// ---------------- adaptive conv: one block = one output row, all M=384 ----------------
// LDS-staged B (3 rows x 84 px x 64ch chunk, XOR-swizzled), A streamed from L2.
__global__ __launch_bounds__(512) void ad_conv_kernel(
    const u16* __restrict__ A, const u16* __restrict__ featP,
    u16* __restrict__ outP, const float* __restrict__ fv) {
  __shared__ u16 lds[3 * 84 * 64];                 // 32256 B
  char* lb = (char*)lds;
  int h = blockIdx.x & 63; int b = blockIdx.x >> 6;
  int tid = threadIdx.x;
  int lane = tid & 63; int wv = tid >> 6;          // 8 waves
  int l15 = lane & 15, kq = lane >> 4;

  f32x4 acc[3][5];
#pragma unroll
  for (int i = 0; i < 3; ++i)
#pragma unroll
    for (int j = 0; j < 5; ++j) acc[i][j] = (f32x4){0.f, 0.f, 0.f, 0.f};

  const u16* fb = featP + (size_t)b * PB;

  for (int c = 0; c < 3; ++c) {                    // 64-ch K chunks
    __syncthreads();
    // stage 3 rows x 84 px x 64 ch = 2016 x 16B chunks
#pragma unroll
    for (int it = 0; it < 4; ++it) {
      int idx = it * 512 + tid;
      if (idx < 2016) {
        int slot = idx & 7; int q = (idx >> 3) % 84; int row = idx / 672;
        bf16x8 v = *(const bf16x8*)(fb + ((size_t)(h + 1 + row) * WP + q) * KC + c * 64 + slot * 8);
        int byte = (((row * 84 + q) * 8 + slot) * 16) ^ ((q & 7) << 4);
        *(bf16x8*)(lb + byte) = v;
      }
    }
    __syncthreads();
#pragma unroll
    for (int ty = 0; ty < 3; ++ty)
#pragma unroll
      for (int tx = 0; tx < 3; ++tx) {
        const u16* At = A + ((size_t)((ty * 3 + tx) * 384 + wv * 48 + l15)) * KC + c * 64 + kq * 8;
#pragma unroll
        for (int half = 0; half < 2; ++half) {
          bf16x8 av[3], bv[5];
#pragma unroll
          for (int fm = 0; fm < 3; ++fm)
            av[fm] = *(const bf16x8*)(At + fm * 16 * KC + half * 32);
#pragma unroll
          for (int fn = 0; fn < 5; ++fn) {
            int q = fn * 16 + l15 + tx + 1;
            int byte = (((ty * 84 + q) * 8 + half * 4 + kq) * 16) ^ ((q & 7) << 4);
            bv[fn] = *(const bf16x8*)(lb + byte);
          }
#pragma unroll
          for (int fm = 0; fm < 3; ++fm)
#pragma unroll
            for (int fn = 0; fn < 5; ++fn)
              acc[fm][fn] = __builtin_amdgcn_mfma_f32_16x16x32_bf16(av[fm], bv[fn], acc[fm][fn], 0, 0, 0);
        }
      }
  }

  // epilogue: pair-combine rows (2i, 2i+1) -> relu(fv*W + B) -> bf16 NHWC padded
#pragma unroll
  for (int fm = 0; fm < 3; ++fm) {
    int rbase = wv * 48 + fm * 16 + kq * 4;
    int i0 = rbase >> 1;
#pragma unroll
    for (int fn = 0; fn < 5; ++fn) {
      int ow = fn * 16 + l15;
      u16* dst = outP + ((size_t)(b * HP + h + 2) * WP + (ow + 2)) * KC;
#pragma unroll
      for (int pr = 0; pr < 2; ++pr) {
        int i = i0 + pr;
        if (i < CW) {
          float v = fv[b * CW + i] * acc[fm][fn][2 * pr] + acc[fm][fn][2 * pr + 1];
          dst[i] = f2b(fmaxf(v, 0.f));
        }
      }
    }
  }
}

// ---------------- MFMA implicit-GEMM conv over padded NHWC bf16 ----------------
// EPI 0: fp32 NCHW + relu; EPI 2: bf16 NHWC padded + relu.
template<int TY, int TX, int S, int OH, int OW, int M, int BM, int BN, int POFF,
         int KCIN, int HPIN, int WPIN, int HPOUT, int WPOUT, int KCOUT, int EPI>
__global__ __launch_bounds__(256) void gemm_conv(
    const u16* __restrict__ A, const u16* __restrict__ featP,
    float* __restrict__ outF, u16* __restrict__ outP,
    const float* __restrict__ fv, int MT, int NT) {
  constexpr int WM = BM / 2, WN = BN / 2, FM = WM / 16, FN = WN / 16;
  constexpr int NKC = KCIN / 32;
  int bid = blockIdx.x;
  int mt = bid % MT; int rest = bid / MT; int nt = rest % NT; int b = rest / NT;
  int lane = threadIdx.x & 63; int wv = threadIdx.x >> 6;
  int wm = wv >> 1, wn = wv & 1;
  int l15 = lane & 15, kq = lane >> 4;

  f32x4 acc[FM][FN];
#pragma unroll
  for (int i = 0; i < FM; ++i)
#pragma unroll
    for (int j = 0; j < FN; ++j) acc[i][j] = (f32x4){0.f, 0.f, 0.f, 0.f};

  const u16* Abase = A + (size_t)(mt * BM + wm * WM + l15) * KCIN + kq * 8;
  const u16* fb = featP + (size_t)b * (HPIN * WPIN * KCIN) + kq * 8;

  int ohh[FN], oww[FN];
#pragma unroll
  for (int fn = 0; fn < FN; ++fn) {
    int p = nt * BN + wn * WN + fn * 16 + l15;
    ohh[fn] = p / OW; oww[fn] = p % OW;
  }

  for (int ty = 0; ty < TY; ++ty)
    for (int tx = 0; tx < TX; ++tx) {
      const u16* At = Abase + (size_t)((ty * TX + tx) * M) * KCIN;
      const u16* Bt[FN];
#pragma unroll
      for (int fn = 0; fn < FN; ++fn) {
        int hi = ohh[fn] * S + ty + POFF;
        int wi = oww[fn] * S + tx + POFF;
        Bt[fn] = fb + (size_t)(hi * WPIN + wi) * KCIN;
      }
#pragma unroll
      for (int kc = 0; kc < NKC; ++kc) {
        bf16x8 av[FM], bv[FN];
#pragma unroll
        for (int fm = 0; fm < FM; ++fm)
          av[fm] = *(const bf16x8*)(At + fm * 16 * KCIN + kc * 32);
#pragma unroll
        for (int fn = 0; fn < FN; ++fn)
          bv[fn] = *(const bf16x8*)(Bt[fn] + kc * 32);
#pragma unroll
        for (int fm = 0; fm < FM; ++fm)
#pragma unroll
          for (int fn = 0; fn < FN; ++fn)
            acc[fm][fn] = __builtin_amdgcn_mfma_f32_16x16x32_bf16(av[fm], bv[fn], acc[fm][fn], 0, 0, 0);
      }
    }

  if constexpr (EPI == 2) {
#pragma unroll
    for (int fm = 0; fm < FM; ++fm) {
      int oc0 = mt * BM + wm * WM + fm * 16 + kq * 4;
#pragma unroll
      for (int fn = 0; fn < FN; ++fn) {
        u16* dst = outP + ((size_t)(b * HPOUT + ohh[fn] + 2) * WPOUT + (oww[fn] + 2)) * KCOUT + oc0;
#pragma unroll
        for (int r = 0; r < 4; ++r)
          dst[r] = f2b(fmaxf(acc[fm][fn][r], 0.f));
      }
    }
  } else {
#pragma unroll
    for (int fm = 0; fm < FM; ++fm) {
      int oc0 = mt * BM + wm * WM + fm * 16 + kq * 4;
#pragma unroll
      for (int fn = 0; fn < FN; ++fn) {
#pragma unroll
        for (int r = 0; r < 4; ++r) {
          float v = fmaxf(acc[fm][fn][r], 0.f);
          outF[(((size_t)b * M + oc0 + r) * OH + ohh[fn]) * OW + oww[fn]] = v;
        }
      }
    }
  }
}

// ---------------- conv3+mean fold, step 1: 9-bin tap sums of hb ----------------
__global__ void tapsum_kernel(const float* __restrict__ hb, float* __restrict__ Sm) {
  int b = blockIdx.x >> 6; int ic = blockIdx.x & 63; int lane = threadIdx.x;
  const float* p = hb + ((size_t)(b * 64 + ic)) * 320;
  float s[9];
#pragma unroll
  for (int t = 0; t < 9; ++t) s[t] = 0.f;
  for (int i = lane; i < 320; i += 64) {
    int ih = i / 20, iw = i % 20;
    float v = p[i];
#pragma unroll
    for (int ky = 0; ky < 3; ++ky) {
      int t2 = ih + 1 - ky;
      if (t2 < 0 || t2 > 14 || (t2 & 1)) continue;
#pragma unroll
      for (int kx = 0; kx < 3; ++kx) {
        int t3 = iw + 1 - kx;
        if (t3 < 0 || t3 > 18 || (t3 & 1)) continue;
        s[ky * 3 + kx] += v;
      }
    }
  }
#pragma unroll
  for (int t = 0; t < 9; ++t)
#pragma unroll
    for (int off = 32; off > 0; off >>= 1) s[t] += __shfl_down(s[t], off);
  if (lane == 0) {
#pragma unroll
    for (int t = 0; t < 9; ++t) Sm[(b * 64 + ic) * 9 + t] = s[t];
  }
}

// ---------------- step 2: fv[b][o] = (1/80) * sum_{ic,t} w3[o,ic,t]*S[b,ic,t] ----------------
__global__ void gemv_fv(const float* __restrict__ w3, const float* __restrict__ Sm,
                        float* __restrict__ fv, int OC) {
  int o = blockIdx.x % OC; int b = blockIdx.x / OC; int lane = threadIdx.x;
  const float* wp = w3 + ((size_t)o * 64 + lane) * 9;
  const float* sp = Sm + ((size_t)b * 64 + lane) * 9;
  float acc = 0.f;
#pragma unroll
  for (int t = 0; t < 9; ++t) acc += wp[t] * sp[t];
#pragma unroll
  for (int off = 32; off > 0; off >>= 1) acc += __shfl_down(acc, off);
  if (lane == 0) fv[b * OC + o] = acc * (1.0f / 80.0f);
}

// ---------------- final: out = fv2*wxf_w + wxf_b ----------------
__global__ void final_kernel(const float* __restrict__ fv, const float* __restrict__ ww,
                             const float* __restrict__ wb, float* __restrict__ out) {
  int idx = blockIdx.x * blockDim.x + threadIdx.x;
  if (idx >= B * 64 * 576) return;
  int kk = idx % 576; int i = (idx / 576) % 64; int b = idx / (576 * 64);
  out[idx] = fv[b * 64 + i] * ww[i * 576 + kk] + wb[i * 576 + kk];
}

extern "C" void kernel_launch(void* const* d_in, const int* in_sizes, int n_in,
                              void* d_out, int out_size, void* d_ws, size_t ws_size,
                              hipStream_t stream) {
  const float* x0    = (const float*)d_in[0];
  const float* y0    = (const float*)d_in[1];
  const float* x     = (const float*)d_in[2];
  const float* y     = (const float*)d_in[3];
  const float* w1a   = (const float*)d_in[4];
  const float* w1b   = (const float*)d_in[5];
  const float* w1c   = (const float*)d_in[6];
  const float* w2a   = (const float*)d_in[7];
  const float* w2b   = (const float*)d_in[8];
  const float* w2c   = (const float*)d_in[9];
  const float* wx_w  = (const float*)d_in[10];
  const float* wx_b  = (const float*)d_in[11];
  const float* wxf_w = (const float*)d_in[12];
  const float* wxf_b = (const float*)d_in[13];
  float* out = (float*)d_out;

  char* base = (char*)d_ws;
  size_t off = 0;
  auto take = [&](size_t bytes) -> char* {
    char* p = base + off; off += (bytes + 255) & ~(size_t)255; return p;
  };
  u16*   featP1 = (u16*)take((size_t)B * PB * 2);
  float* xpT    = (float*)take((size_t)B * H * W * C * 4);
  float* ypT    = (float*)take((size_t)B * H * W * C * 4);
  u16*   featP2 = (u16*)(void*)xpT;                 // alias: 21 MB >= 17.55 MB
  u16*   Aad    = (u16*)take((size_t)9 * 384 * 192 * 2);
  u16*   A5a    = (u16*)take((size_t)25 * 64 * 192 * 2);
  u16*   A5b    = (u16*)take((size_t)25 * 64 * 192 * 2);
  u16*   A5b1   = (u16*)take((size_t)25 * 64 * 64 * 2);
  u16*   A5b2   = (u16*)take((size_t)25 * 64 * 64 * 2);
  u16*   haP    = (u16*)take((size_t)B * HA * WA * 64 * 2);
  float* hb     = (float*)take((size_t)B * 64 * 320 * 4);
  float* Sm     = (float*)take((size_t)B * 64 * 9 * 4);
  float* fv1    = (float*)take((size_t)B * CW * 4);
  float* fv2    = (float*)take((size_t)B * 64 * 4);
  if (off > ws_size) return;

  const int TB = 256;
  int nfull8 = (B * PB) / 8;
  int nha8 = (B * HA * WA * 64) / 8;

  zfill8<<<(nfull8 + TB - 1) / TB, TB, 0, stream>>>(featP1, nfull8);
  zfill8<<<(nha8 + TB - 1) / TB, TB, 0, stream>>>(haP, nha8);
  {
    int n = B * C * H * W;
    pool2_nhwc<<<(n + TB - 1) / TB, TB, 0, stream>>>(x0, xpT);
    pool2_nhwc<<<(n + TB - 1) / TB, TB, 0, stream>>>(y0, ypT);
  }
  {
    int n = B * H * W * 49;
    corr_fill<<<(n + TB - 1) / TB, TB, 0, stream>>>(xpT, ypT, featP1);
    int n2 = B * 128 * H * W;
    copyxy<<<(n2 + TB - 1) / TB, TB, 0, stream>>>(x, y, featP1);
  }
  zfill8<<<(nfull8 + TB - 1) / TB, TB, 0, stream>>>(featP2, nfull8);
  pack_Aad<<<(9 * 384 * 192 + TB - 1) / TB, TB, 0, stream>>>(wx_w, wx_b, Aad);
  pack_w5<<<(25 * 64 * 192 + TB - 1) / TB, TB, 0, stream>>>(w1a, A5a, 192, CW);
  pack_w5<<<(25 * 64 * 192 + TB - 1) / TB, TB, 0, stream>>>(w2a, A5b, 192, CW);
  pack_w5<<<(25 * 64 * 64 + TB - 1) / TB, TB, 0, stream>>>(w1b, A5b1, 64, 64);
  pack_w5<<<(25 * 64 * 64 + TB - 1) / TB, TB, 0, stream>>>(w2b, A5b2, 64, 64);

  // ---- branch 1 ----
  gemm_conv<5, 5, 2, 32, 40, 64, 64, 64, 0, 192, 68, 84, HA, WA, 64, 2>
      <<<20 * B, TB, 0, stream>>>(A5a, featP1, nullptr, haP, nullptr, 1, 20);
  gemm_conv<5, 5, 2, 16, 20, 64, 64, 64, 0, 64, HA, WA, 0, 0, 0, 0>
      <<<5 * B, TB, 0, stream>>>(A5b1, haP, hb, nullptr, nullptr, 1, 5);
  tapsum_kernel<<<B * 64, 64, 0, stream>>>(hb, Sm);
  gemv_fv<<<B * CW, 64, 0, stream>>>(w1c, Sm, fv1, CW);

  // ---- adaptive conv (LDS-staged, whole-M per block) ----
  ad_conv_kernel<<<64 * B, 512, 0, stream>>>(Aad, featP1, featP2, fv1);

  // ---- branch 2 ----
  gemm_conv<5, 5, 2, 32, 40, 64, 64, 64, 0, 192, 68, 84, HA, WA, 64, 2>
      <<<20 * B, TB, 0, stream>>>(A5b, featP2, nullptr, haP, nullptr, 1, 20);
  gemm_conv<5, 5, 2, 16, 20, 64, 64, 64, 0, 64, HA, WA, 0, 0, 0, 0>
      <<<5 * B, TB, 0, stream>>>(A5b2, haP, hb, nullptr, nullptr, 1, 5);
  tapsum_kernel<<<B * 64, 64, 0, stream>>>(hb, Sm);
  gemv_fv<<<B * 64, 64, 0, stream>>>(w2c, Sm, fv2, 64);

  // ---- final output ----
  final_kernel<<<(B * 64 * 576 + TB - 1) / TB, TB, 0, stream>>>(fv2, wxf_w, wxf_b, out);
}

// Round 5
// 470.349 us; speedup vs baseline: 17.1239x; 1.0059x over previous
//
#include <hip/hip_runtime.h>

typedef unsigned short u16;
typedef __attribute__((ext_vector_type(8))) short bf16x8;
typedef __attribute__((ext_vector_type(4))) float f32x4;

static constexpr int B  = 8;
static constexpr int C  = 64;
static constexpr int CW = 177;
static constexpr int H  = 64, W  = 80;
static constexpr int HP = 68, WP = 84, KC = 192;   // feat padded NHWC
static constexpr int PB = HP * WP * KC;
static constexpr int HA = 36, WA = 44;             // conv5a out padded (32x40 + halo2)

__device__ __forceinline__ u16 f2b(float f) {
  union { float f; unsigned u; } v; v.f = f;
  unsigned u = v.u;
  return (u16)((u + 0x7FFF + ((u >> 16) & 1)) >> 16);
}

__global__ void zfill8(u16* __restrict__ p, int n8) {
  int i = blockIdx.x * blockDim.x + threadIdx.x;
  if (i < n8) { bf16x8 z = 0; ((bf16x8*)p)[i] = z; }
}

// ---------------- pool 2x2 mean -> NHWC fp32 (x0 and y0 fused) ----------------
__global__ void pool2_nhwc(const float* __restrict__ x0, const float* __restrict__ y0,
                           float* __restrict__ xpT, float* __restrict__ ypT) {
  int idx = blockIdx.x * blockDim.x + threadIdx.x;
  int n1 = B * C * H * W;
  if (idx >= 2 * n1) return;
  const float* in = (idx < n1) ? x0 : y0;
  float* out = (idx < n1) ? xpT : ypT;
  int id = (idx < n1) ? idx : idx - n1;
  int w = id % W; int h = (id / W) % H; int c = (id / (W * H)) % C; int b = id / (W * H * C);
  const float* p = in + ((size_t)(b * C + c) * 128 + 2 * h) * 160 + 2 * w;
  float v = 0.25f * (p[0] + p[1] + p[160] + p[161]);
  out[((size_t)(b * H + h) * W + w) * C + c] = v;
}

// ---------------- corr -> featP channels 0..48 ----------------
__global__ void corr_fill(const float* __restrict__ xpT, const float* __restrict__ ypT,
                          u16* __restrict__ featP) {
  int idx = blockIdx.x * blockDim.x + threadIdx.x;
  if (idx >= B * H * W * 49) return;
  int o = idx % 49; int p = idx / 49;
  int w = p % W; int h = (p / W) % H; int b = p / (W * H);
  int dy = (o / 7) * 2 - 6, dx = (o % 7) * 2 - 6;
  int hh = h + dy, ww = w + dx;
  float s = 0.f;
  if (hh >= 0 && hh < H && ww >= 0 && ww < W) {
    const float4* xv = (const float4*)(xpT + ((size_t)(b * H + h) * W + w) * C);
    const float4* yv = (const float4*)(ypT + ((size_t)(b * H + hh) * W + ww) * C);
#pragma unroll
    for (int i = 0; i < 16; ++i) {
      float4 a = xv[i], q = yv[i];
      s += a.x * q.x + a.y * q.y + a.z * q.z + a.w * q.w;
    }
  }
  s *= (1.0f / 64.0f);
  featP[((size_t)(b * HP + h + 2) * WP + (w + 2)) * KC + o] = f2b(s);
}

// ---------------- x,y -> featP channels 49..176 ----------------
__global__ void copyxy(const float* __restrict__ x, const float* __restrict__ y,
                       u16* __restrict__ featP) {
  int idx = blockIdx.x * blockDim.x + threadIdx.x;
  if (idx >= B * 128 * H * W) return;
  int pix = idx % (H * W); int c2 = (idx / (H * W)) % 128; int b = idx / (H * W * 128);
  int h = pix / W, w = pix % W;
  float v = (c2 < 64) ? x[((size_t)(b * C + c2) * H + h) * W + w]
                      : y[((size_t)(b * C + (c2 - 64)) * H + h) * W + w];
  featP[((size_t)(b * HP + h + 2) * WP + (w + 2)) * KC + 49 + c2] = f2b(v);
}

// ---------------- pack adaptive weights: Aad[kk][r][j] ----------------
__global__ void pack_Aad(const float* __restrict__ ww, const float* __restrict__ wb,
                         u16* __restrict__ Aad) {
  int idx = blockIdx.x * blockDim.x + threadIdx.x;
  if (idx >= 9 * 384 * 192) return;
  int j = idx % 192; int r = (idx / 192) % 384; int kk = idx / (192 * 384);
  int i = r >> 1;
  float v = 0.f;
  if (j < CW && i < CW) {
    const float* src = (r & 1) ? wb : ww;
    v = src[(size_t)i * (CW * 9) + j * 9 + kk];
  }
  Aad[idx] = f2b(v);
}

// ---------------- pack 5x5 weights: A[kk][i][KCA] ----------------
__global__ void pack_w5(const float* __restrict__ w, u16* __restrict__ A, int KCA, int ICR) {
  int idx = blockIdx.x * blockDim.x + threadIdx.x;
  if (idx >= 25 * 64 * KCA) return;
  int j = idx % KCA; int i = (idx / KCA) % 64; int kk = idx / (KCA * 64);
  int ky = kk / 5, kx = kk % 5;
  float v = (j < ICR) ? w[(((size_t)i * ICR + j) * 5 + ky) * 5 + kx] : 0.f;
  A[idx] = f2b(v);
}

// ---------------- adaptive conv v2: block = 2 output rows, all M=384, FM=6 ----------------
// 8 waves = 4 M-groups(96 rows) x 2 out-rows. 4 input rows staged in LDS (XOR-swizzled).
__global__ __launch_bounds__(512, 2) void ad_conv_kernel(
    const u16* __restrict__ A, const u16* __restrict__ featP,
    u16* __restrict__ outP, const float* __restrict__ fv) {
  __shared__ u16 lds[4 * 84 * 64];                 // 43008 B
  char* lb = (char*)lds;
  // XCD swizzle: grid 256, same-b blocks on same XCD
  int bid = (int)(blockIdx.x % 8) * 32 + (int)(blockIdx.x / 8);
  int h2 = bid & 31; int b = bid >> 5;
  int r0 = h2 * 2;
  int tid = threadIdx.x;
  int lane = tid & 63; int wv = tid >> 6;          // 8 waves
  int wm = wv & 3; int rowsel = wv >> 2;
  int l15 = lane & 15, kq = lane >> 4;

  f32x4 acc[6][5];
#pragma unroll
  for (int i = 0; i < 6; ++i)
#pragma unroll
    for (int j = 0; j < 5; ++j) acc[i][j] = (f32x4){0.f, 0.f, 0.f, 0.f};

  const u16* fb = featP + (size_t)b * PB;

  for (int c = 0; c < 3; ++c) {                    // 64-ch K chunks
    __syncthreads();
    // stage 4 rows x 84 px x 64 ch = 2688 x 16B chunks
#pragma unroll
    for (int it = 0; it < 6; ++it) {
      int idx = it * 512 + tid;
      if (idx < 2688) {
        int slot = idx & 7; int q = (idx >> 3) % 84; int row = idx / 672;
        bf16x8 v = *(const bf16x8*)(fb + ((size_t)(r0 + 1 + row) * WP + q) * KC + c * 64 + slot * 8);
        int byte = (idx * 16) ^ ((q & 7) << 4);
        *(bf16x8*)(lb + byte) = v;
      }
    }
    __syncthreads();
#pragma unroll
    for (int ty = 0; ty < 3; ++ty)
#pragma unroll
      for (int tx = 0; tx < 3; ++tx) {
        const u16* At = A + ((size_t)((ty * 3 + tx) * 384 + wm * 96 + l15)) * KC + c * 64 + kq * 8;
        int rr = rowsel + ty;
#pragma unroll
        for (int half = 0; half < 2; ++half) {
          bf16x8 av[6], bv[5];
#pragma unroll
          for (int fm = 0; fm < 6; ++fm)
            av[fm] = *(const bf16x8*)(At + fm * 16 * KC + half * 32);
#pragma unroll
          for (int fn = 0; fn < 5; ++fn) {
            int q = fn * 16 + l15 + tx + 1;
            int byte = (((rr * 84 + q) * 8 + half * 4 + kq) * 16) ^ ((q & 7) << 4);
            bv[fn] = *(const bf16x8*)(lb + byte);
          }
#pragma unroll
          for (int fm = 0; fm < 6; ++fm)
#pragma unroll
            for (int fn = 0; fn < 5; ++fn)
              acc[fm][fn] = __builtin_amdgcn_mfma_f32_16x16x32_bf16(av[fm], bv[fn], acc[fm][fn], 0, 0, 0);
        }
      }
  }

  // epilogue: pair-combine rows (2i, 2i+1) -> relu(fv*W + B) -> bf16 NHWC padded
  int orow = r0 + rowsel;
#pragma unroll
  for (int fm = 0; fm < 6; ++fm) {
    int rbase = wm * 96 + fm * 16 + kq * 4;
    int i0 = rbase >> 1;
#pragma unroll
    for (int fn = 0; fn < 5; ++fn) {
      int ow = fn * 16 + l15;
      u16* dst = outP + ((size_t)(b * HP + orow + 2) * WP + (ow + 2)) * KC;
#pragma unroll
      for (int pr = 0; pr < 2; ++pr) {
        int i = i0 + pr;
        if (i < CW) {
          float v = fv[b * CW + i] * acc[fm][fn][2 * pr] + acc[fm][fn][2 * pr + 1];
          dst[i] = f2b(fmaxf(v, 0.f));
        }
      }
    }
  }
}

// ---------------- MFMA implicit-GEMM conv over padded NHWC bf16 ----------------
// kc-outer / taps-inner for L1 reuse of the B-tile across taps.
// EPI 0: fp32 NCHW + relu; EPI 2: bf16 NHWC padded + relu.
template<int TY, int TX, int S, int OH, int OW, int M, int BM, int BN, int POFF,
         int KCIN, int HPIN, int WPIN, int HPOUT, int WPOUT, int KCOUT, int EPI>
__global__ __launch_bounds__(256) void gemm_conv(
    const u16* __restrict__ A, const u16* __restrict__ featP,
    float* __restrict__ outF, u16* __restrict__ outP,
    const float* __restrict__ fv, int MT, int NT) {
  constexpr int WM = BM / 2, WN = BN / 2, FM = WM / 16, FN = WN / 16;
  constexpr int NKC = KCIN / 32;
  // XCD swizzle (grid is always a multiple of 8 here)
  int nwg = gridDim.x;
  int bid = (int)(blockIdx.x % 8) * (nwg / 8) + (int)(blockIdx.x / 8);
  int mt = bid % MT; int rest = bid / MT; int nt = rest % NT; int b = rest / NT;
  int lane = threadIdx.x & 63; int wv = threadIdx.x >> 6;
  int wm = wv >> 1, wn = wv & 1;
  int l15 = lane & 15, kq = lane >> 4;

  f32x4 acc[FM][FN];
#pragma unroll
  for (int i = 0; i < FM; ++i)
#pragma unroll
    for (int j = 0; j < FN; ++j) acc[i][j] = (f32x4){0.f, 0.f, 0.f, 0.f};

  const u16* Abase = A + (size_t)(mt * BM + wm * WM + l15) * KCIN + kq * 8;
  const u16* fb = featP + (size_t)b * (HPIN * WPIN * KCIN) + kq * 8;

  int ohh[FN], oww[FN];
#pragma unroll
  for (int fn = 0; fn < FN; ++fn) {
    int p = nt * BN + wn * WN + fn * 16 + l15;
    ohh[fn] = p / OW; oww[fn] = p % OW;
  }

  for (int kc = 0; kc < NKC; ++kc) {
    for (int ty = 0; ty < TY; ++ty)
      for (int tx = 0; tx < TX; ++tx) {
        const u16* At = Abase + (size_t)((ty * TX + tx) * M) * KCIN + kc * 32;
        bf16x8 av[FM], bv[FN];
#pragma unroll
        for (int fm = 0; fm < FM; ++fm)
          av[fm] = *(const bf16x8*)(At + fm * 16 * KCIN);
#pragma unroll
        for (int fn = 0; fn < FN; ++fn) {
          int hi = ohh[fn] * S + ty + POFF;
          int wi = oww[fn] * S + tx + POFF;
          bv[fn] = *(const bf16x8*)(fb + (size_t)(hi * WPIN + wi) * KCIN + kc * 32);
        }
#pragma unroll
        for (int fm = 0; fm < FM; ++fm)
#pragma unroll
          for (int fn = 0; fn < FN; ++fn)
            acc[fm][fn] = __builtin_amdgcn_mfma_f32_16x16x32_bf16(av[fm], bv[fn], acc[fm][fn], 0, 0, 0);
      }
  }

  if constexpr (EPI == 2) {
#pragma unroll
    for (int fm = 0; fm < FM; ++fm) {
      int oc0 = mt * BM + wm * WM + fm * 16 + kq * 4;
#pragma unroll
      for (int fn = 0; fn < FN; ++fn) {
        u16* dst = outP + ((size_t)(b * HPOUT + ohh[fn] + 2) * WPOUT + (oww[fn] + 2)) * KCOUT + oc0;
#pragma unroll
        for (int r = 0; r < 4; ++r)
          dst[r] = f2b(fmaxf(acc[fm][fn][r], 0.f));
      }
    }
  } else {
#pragma unroll
    for (int fm = 0; fm < FM; ++fm) {
      int oc0 = mt * BM + wm * WM + fm * 16 + kq * 4;
#pragma unroll
      for (int fn = 0; fn < FN; ++fn) {
#pragma unroll
        for (int r = 0; r < 4; ++r) {
          float v = fmaxf(acc[fm][fn][r], 0.f);
          outF[(((size_t)b * M + oc0 + r) * OH + ohh[fn]) * OW + oww[fn]] = v;
        }
      }
    }
  }
}

// ---------------- conv3+mean fold, step 1: 9-bin tap sums of hb ----------------
__global__ void tapsum_kernel(const float* __restrict__ hb, float* __restrict__ Sm) {
  int b = blockIdx.x >> 6; int ic = blockIdx.x & 63; int lane = threadIdx.x;
  const float* p = hb + ((size_t)(b * 64 + ic)) * 320;
  float s[9];
#pragma unroll
  for (int t = 0; t < 9; ++t) s[t] = 0.f;
  for (int i = lane; i < 320; i += 64) {
    int ih = i / 20, iw = i % 20;
    float v = p[i];
#pragma unroll
    for (int ky = 0; ky < 3; ++ky) {
      int t2 = ih + 1 - ky;
      if (t2 < 0 || t2 > 14 || (t2 & 1)) continue;
#pragma unroll
      for (int kx = 0; kx < 3; ++kx) {
        int t3 = iw + 1 - kx;
        if (t3 < 0 || t3 > 18 || (t3 & 1)) continue;
        s[ky * 3 + kx] += v;
      }
    }
  }
#pragma unroll
  for (int t = 0; t < 9; ++t)
#pragma unroll
    for (int off = 32; off > 0; off >>= 1) s[t] += __shfl_down(s[t], off);
  if (lane == 0) {
#pragma unroll
    for (int t = 0; t < 9; ++t) Sm[(b * 64 + ic) * 9 + t] = s[t];
  }
}

// ---------------- step 2: fv[b][o] = (1/80) * sum_{ic,t} w3[o,ic,t]*S[b,ic,t] ----------------
__global__ void gemv_fv(const float* __restrict__ w3, const float* __restrict__ Sm,
                        float* __restrict__ fv, int OC) {
  int o = blockIdx.x % OC; int b = blockIdx.x / OC; int lane = threadIdx.x;
  const float* wp = w3 + ((size_t)o * 64 + lane) * 9;
  const float* sp = Sm + ((size_t)b * 64 + lane) * 9;
  float acc = 0.f;
#pragma unroll
  for (int t = 0; t < 9; ++t) acc += wp[t] * sp[t];
#pragma unroll
  for (int off = 32; off > 0; off >>= 1) acc += __shfl_down(acc, off);
  if (lane == 0) fv[b * OC + o] = acc * (1.0f / 80.0f);
}

// ---------------- final: out = fv2*wxf_w + wxf_b ----------------
__global__ void final_kernel(const float* __restrict__ fv, const float* __restrict__ ww,
                             const float* __restrict__ wb, float* __restrict__ out) {
  int idx = blockIdx.x * blockDim.x + threadIdx.x;
  if (idx >= B * 64 * 576) return;
  int kk = idx % 576; int i = (idx / 576) % 64; int b = idx / (576 * 64);
  out[idx] = fv[b * 64 + i] * ww[i * 576 + kk] + wb[i * 576 + kk];
}

extern "C" void kernel_launch(void* const* d_in, const int* in_sizes, int n_in,
                              void* d_out, int out_size, void* d_ws, size_t ws_size,
                              hipStream_t stream) {
  const float* x0    = (const float*)d_in[0];
  const float* y0    = (const float*)d_in[1];
  const float* x     = (const float*)d_in[2];
  const float* y     = (const float*)d_in[3];
  const float* w1a   = (const float*)d_in[4];
  const float* w1b   = (const float*)d_in[5];
  const float* w1c   = (const float*)d_in[6];
  const float* w2a   = (const float*)d_in[7];
  const float* w2b   = (const float*)d_in[8];
  const float* w2c   = (const float*)d_in[9];
  const float* wx_w  = (const float*)d_in[10];
  const float* wx_b  = (const float*)d_in[11];
  const float* wxf_w = (const float*)d_in[12];
  const float* wxf_b = (const float*)d_in[13];
  float* out = (float*)d_out;

  char* base = (char*)d_ws;
  size_t off = 0;
  auto take = [&](size_t bytes) -> char* {
    char* p = base + off; off += (bytes + 255) & ~(size_t)255; return p;
  };
  u16*   featP1 = (u16*)take((size_t)B * PB * 2);
  float* xpT    = (float*)take((size_t)B * H * W * C * 4);
  float* ypT    = (float*)take((size_t)B * H * W * C * 4);
  u16*   featP2 = (u16*)(void*)xpT;                 // alias: 21 MB >= 17.55 MB
  u16*   Aad    = (u16*)take((size_t)9 * 384 * 192 * 2);
  u16*   A5a    = (u16*)take((size_t)25 * 64 * 192 * 2);
  u16*   A5b    = (u16*)take((size_t)25 * 64 * 192 * 2);
  u16*   A5b1   = (u16*)take((size_t)25 * 64 * 64 * 2);
  u16*   A5b2   = (u16*)take((size_t)25 * 64 * 64 * 2);
  u16*   haP    = (u16*)take((size_t)B * HA * WA * 64 * 2);
  float* hb     = (float*)take((size_t)B * 64 * 320 * 4);
  float* Sm     = (float*)take((size_t)B * 64 * 9 * 4);
  float* fv1    = (float*)take((size_t)B * CW * 4);
  float* fv2    = (float*)take((size_t)B * 64 * 4);
  if (off > ws_size) return;

  const int TB = 256;
  int nfull8 = (B * PB) / 8;
  int nha8 = (B * HA * WA * 64) / 8;

  zfill8<<<(nfull8 + TB - 1) / TB, TB, 0, stream>>>(featP1, nfull8);
  zfill8<<<(nha8 + TB - 1) / TB, TB, 0, stream>>>(haP, nha8);
  {
    int n = 2 * B * C * H * W;
    pool2_nhwc<<<(n + TB - 1) / TB, TB, 0, stream>>>(x0, y0, xpT, ypT);
  }
  {
    int n = B * H * W * 49;
    corr_fill<<<(n + TB - 1) / TB, TB, 0, stream>>>(xpT, ypT, featP1);
    int n2 = B * 128 * H * W;
    copyxy<<<(n2 + TB - 1) / TB, TB, 0, stream>>>(x, y, featP1);
  }
  zfill8<<<(nfull8 + TB - 1) / TB, TB, 0, stream>>>(featP2, nfull8);
  pack_Aad<<<(9 * 384 * 192 + TB - 1) / TB, TB, 0, stream>>>(wx_w, wx_b, Aad);
  pack_w5<<<(25 * 64 * 192 + TB - 1) / TB, TB, 0, stream>>>(w1a, A5a, 192, CW);
  pack_w5<<<(25 * 64 * 192 + TB - 1) / TB, TB, 0, stream>>>(w2a, A5b, 192, CW);
  pack_w5<<<(25 * 64 * 64 + TB - 1) / TB, TB, 0, stream>>>(w1b, A5b1, 64, 64);
  pack_w5<<<(25 * 64 * 64 + TB - 1) / TB, TB, 0, stream>>>(w2b, A5b2, 64, 64);

  // ---- branch 1 ----
  gemm_conv<5, 5, 2, 32, 40, 64, 64, 64, 0, 192, 68, 84, HA, WA, 64, 2>
      <<<20 * B, TB, 0, stream>>>(A5a, featP1, nullptr, haP, nullptr, 1, 20);
  gemm_conv<5, 5, 2, 16, 20, 64, 64, 64, 0, 64, HA, WA, 0, 0, 0, 0>
      <<<5 * B, TB, 0, stream>>>(A5b1, haP, hb, nullptr, nullptr, 1, 5);
  tapsum_kernel<<<B * 64, 64, 0, stream>>>(hb, Sm);
  gemv_fv<<<B * CW, 64, 0, stream>>>(w1c, Sm, fv1, CW);

  // ---- adaptive conv (LDS-staged, 2-row blocks, FM=6) ----
  ad_conv_kernel<<<32 * B, 512, 0, stream>>>(Aad, featP1, featP2, fv1);

  // ---- branch 2 ----
  gemm_conv<5, 5, 2, 32, 40, 64, 64, 64, 0, 192, 68, 84, HA, WA, 64, 2>
      <<<20 * B, TB, 0, stream>>>(A5b, featP2, nullptr, haP, nullptr, 1, 20);
  gemm_conv<5, 5, 2, 16, 20, 64, 64, 64, 0, 64, HA, WA, 0, 0, 0, 0>
      <<<5 * B, TB, 0, stream>>>(A5b2, haP, hb, nullptr, nullptr, 1, 5);
  tapsum_kernel<<<B * 64, 64, 0, stream>>>(hb, Sm);
  gemv_fv<<<B * 64, 64, 0, stream>>>(w2c, Sm, fv2, 64);

  // ---- final output ----
  final_kernel<<<(B * 64 * 576 + TB - 1) / TB, TB, 0, stream>>>(fv2, wxf_w, wxf_b, out);
}

// Round 6
// 360.814 us; speedup vs baseline: 22.3223x; 1.3036x over previous
//
#include <hip/hip_runtime.h>

typedef unsigned short u16;
typedef __attribute__((ext_vector_type(8))) short bf16x8;
typedef __attribute__((ext_vector_type(4))) float f32x4;

static constexpr int B  = 8;
static constexpr int C  = 64;
static constexpr int CW = 177;
static constexpr int H  = 64, W  = 80;
static constexpr int HP = 68, WP = 84, KC = 192;   // feat padded NHWC
static constexpr int PB = HP * WP * KC;
static constexpr int HA = 36, WA = 44;             // conv5a out padded (32x40 + halo2)

__device__ __forceinline__ u16 f2b(float f) {
  union { float f; unsigned u; } v; v.f = f;
  unsigned u = v.u;
  return (u16)((u + 0x7FFF + ((u >> 16) & 1)) >> 16);
}

__global__ void zfill8(u16* __restrict__ p, int n8) {
  int i = blockIdx.x * blockDim.x + threadIdx.x;
  if (i < n8) { bf16x8 z = 0; ((bf16x8*)p)[i] = z; }
}

// ---------------- pool 2x2 mean -> NHWC fp32 (x0 and y0 fused) ----------------
__global__ void pool2_nhwc(const float* __restrict__ x0, const float* __restrict__ y0,
                           float* __restrict__ xpT, float* __restrict__ ypT) {
  int idx = blockIdx.x * blockDim.x + threadIdx.x;
  int n1 = B * C * H * W;
  if (idx >= 2 * n1) return;
  const float* in = (idx < n1) ? x0 : y0;
  float* out = (idx < n1) ? xpT : ypT;
  int id = (idx < n1) ? idx : idx - n1;
  int w = id % W; int h = (id / W) % H; int c = (id / (W * H)) % C; int b = id / (W * H * C);
  const float* p = in + ((size_t)(b * C + c) * 128 + 2 * h) * 160 + 2 * w;
  float v = 0.25f * (p[0] + p[1] + p[160] + p[161]);
  out[((size_t)(b * H + h) * W + w) * C + c] = v;
}

// ---------------- corr -> featP channels 0..48 ----------------
__global__ void corr_fill(const float* __restrict__ xpT, const float* __restrict__ ypT,
                          u16* __restrict__ featP) {
  int idx = blockIdx.x * blockDim.x + threadIdx.x;
  if (idx >= B * H * W * 49) return;
  int o = idx % 49; int p = idx / 49;
  int w = p % W; int h = (p / W) % H; int b = p / (W * H);
  int dy = (o / 7) * 2 - 6, dx = (o % 7) * 2 - 6;
  int hh = h + dy, ww = w + dx;
  float s = 0.f;
  if (hh >= 0 && hh < H && ww >= 0 && ww < W) {
    const float4* xv = (const float4*)(xpT + ((size_t)(b * H + h) * W + w) * C);
    const float4* yv = (const float4*)(ypT + ((size_t)(b * H + hh) * W + ww) * C);
#pragma unroll
    for (int i = 0; i < 16; ++i) {
      float4 a = xv[i], q = yv[i];
      s += a.x * q.x + a.y * q.y + a.z * q.z + a.w * q.w;
    }
  }
  s *= (1.0f / 64.0f);
  featP[((size_t)(b * HP + h + 2) * WP + (w + 2)) * KC + o] = f2b(s);
}

// ---------------- x,y -> featP channels 49..176 ----------------
__global__ void copyxy(const float* __restrict__ x, const float* __restrict__ y,
                       u16* __restrict__ featP) {
  int idx = blockIdx.x * blockDim.x + threadIdx.x;
  if (idx >= B * 128 * H * W) return;
  int pix = idx % (H * W); int c2 = (idx / (H * W)) % 128; int b = idx / (H * W * 128);
  int h = pix / W, w = pix % W;
  float v = (c2 < 64) ? x[((size_t)(b * C + c2) * H + h) * W + w]
                      : y[((size_t)(b * C + (c2 - 64)) * H + h) * W + w];
  featP[((size_t)(b * HP + h + 2) * WP + (w + 2)) * KC + 49 + c2] = f2b(v);
}

// ---------------- pack 5x5 weights: A[kk][i][KCA] ----------------
__global__ void pack_w5(const float* __restrict__ w, u16* __restrict__ A, int KCA, int ICR) {
  int idx = blockIdx.x * blockDim.x + threadIdx.x;
  if (idx >= 25 * 64 * KCA) return;
  int j = idx % KCA; int i = (idx / KCA) % 64; int kk = idx / (KCA * 64);
  int ky = kk / 5, kx = kk % 5;
  float v = (j < ICR) ? w[(((size_t)i * ICR + j) * 5 + ky) * 5 + kx] : 0.f;
  A[idx] = f2b(v);
}

// ---------------- materialize per-batch adaptive weights: Awx[b][kk][i192][j192] bf16 ----------------
__global__ void wx_pack(const float* __restrict__ fv, const float* __restrict__ ww,
                        const float* __restrict__ wb, u16* __restrict__ Awx) {
  int idx = blockIdx.x * blockDim.x + threadIdx.x;
  if (idx >= B * 9 * 192 * 192) return;
  int j = idx % 192; int i = (idx / 192) % 192; int kk = (idx / (192 * 192)) % 9;
  int b = idx / (9 * 192 * 192);
  float v = 0.f;
  if (i < CW && j < CW) {
    size_t o = (size_t)i * (CW * 9) + j * 9 + kk;
    v = fv[b * CW + i] * ww[o] + wb[o];
  }
  Awx[idx] = f2b(v);
}

// ---------------- conv5 (s2) ky-split: block = 2 out-rows x 64oc x 80px, one ky ----------------
// partials fp32 pa[ty][b][orow32][ocol40][oc64]
__global__ __launch_bounds__(128, 3) void conv5_split_kernel(
    const u16* __restrict__ A5, const u16* __restrict__ featP, float* __restrict__ pa) {
  __shared__ u16 lds[2 * 84 * 32];                 // 10.5 KB
  char* lb = (char*)lds;
  int bid = (int)(blockIdx.x % 8) * 80 + (int)(blockIdx.x / 8);
  int rp = bid % 16; int ty = (bid / 16) % 5; int b = bid / 80;
  int r0 = rp * 2;
  int tid = threadIdx.x;
  int lane = tid & 63; int wm = tid >> 6;          // 2 waves
  int l15 = lane & 15, kq = lane >> 4;

  f32x4 acc[2][5];
#pragma unroll
  for (int i = 0; i < 2; ++i)
#pragma unroll
    for (int j = 0; j < 5; ++j) acc[i][j] = (f32x4){0.f, 0.f, 0.f, 0.f};

  const u16* fb = featP + (size_t)b * PB;
  int rowg0 = 2 * r0 + ty;                          // padded in-row for local row 0 (+2 for row 1)

  for (int kc = 0; kc < 6; ++kc) {                  // 32-ch K chunks
    __syncthreads();
#pragma unroll
    for (int it = 0; it < 6; ++it) {
      int idx = it * 128 + tid;
      if (idx < 672) {
        int slot = idx & 3; int q = (idx >> 2) % 84; int row = idx / 336;
        bf16x8 v = *(const bf16x8*)(fb + ((size_t)(rowg0 + 2 * row) * WP + q) * KC + kc * 32 + slot * 8);
        int byte = (idx * 16) ^ ((q & 7) << 4);
        *(bf16x8*)(lb + byte) = v;
      }
    }
    __syncthreads();
#pragma unroll
    for (int tx = 0; tx < 5; ++tx) {
      bf16x8 av[2], bv[5];
#pragma unroll
      for (int fm = 0; fm < 2; ++fm)
        av[fm] = *(const bf16x8*)(A5 + ((size_t)((ty * 5 + tx) * 64 + wm * 32 + fm * 16 + l15)) * 192 + kc * 32 + kq * 8);
#pragma unroll
      for (int fn = 0; fn < 5; ++fn) {
        int p = fn * 16 + l15;
        int orow = p / 40, ocol = p % 40;
        int q = ocol * 2 + tx;
        int byte = (((orow * 84 + q) * 4 + kq) * 16) ^ ((q & 7) << 4);
        bv[fn] = *(const bf16x8*)(lb + byte);
      }
#pragma unroll
      for (int fm = 0; fm < 2; ++fm)
#pragma unroll
        for (int fn = 0; fn < 5; ++fn)
          acc[fm][fn] = __builtin_amdgcn_mfma_f32_16x16x32_bf16(av[fm], bv[fn], acc[fm][fn], 0, 0, 0);
    }
  }
#pragma unroll
  for (int fm = 0; fm < 2; ++fm) {
    int oc0 = wm * 32 + fm * 16 + kq * 4;
#pragma unroll
    for (int fn = 0; fn < 5; ++fn) {
      int p = fn * 16 + l15;
      int orow = r0 + p / 40, ocol = p % 40;
      float* dst = pa + (((((size_t)ty * B + b) * 32 + orow) * 40 + ocol) * 64) + oc0;
      *(f32x4*)dst = acc[fm][fn];
    }
  }
}

// ---------------- combine 5 partials -> relu -> bf16 haP (padded NHWC) ----------------
__global__ void combine5(const float* __restrict__ pa, u16* __restrict__ haP) {
  int idx = blockIdx.x * blockDim.x + threadIdx.x;
  if (idx >= B * 32 * 40 * 64) return;
  int oc = idx & 63; int t = idx >> 6;
  int ocol = t % 40; t /= 40; int orow = t % 32; int b = t / 32;
  float s = 0.f;
#pragma unroll
  for (int ty = 0; ty < 5; ++ty)
    s += pa[(((((size_t)ty * B + b) * 32 + orow) * 40 + ocol) * 64) + oc];
  haP[((size_t)(b * HA + orow + 2) * WA + (ocol + 2)) * 64 + oc] = f2b(fmaxf(s, 0.f));
}

// ---------------- adaptive conv v3: per-batch Awx, block = 1 out-row, M=192, 6 waves ----------------
__global__ __launch_bounds__(384, 3) void ad_conv_kernel(
    const u16* __restrict__ Awx, const u16* __restrict__ featP, u16* __restrict__ outP) {
  __shared__ u16 lds[3 * 84 * 64];                 // 32.25 KB
  char* lb = (char*)lds;
  int bid = (int)(blockIdx.x % 8) * 64 + (int)(blockIdx.x / 8);
  int h = bid & 63; int b = bid >> 6;
  int tid = threadIdx.x;
  int lane = tid & 63; int wm = tid >> 6;          // 6 waves = 6 M-groups of 32
  int l15 = lane & 15, kq = lane >> 4;

  f32x4 acc[2][5];
#pragma unroll
  for (int i = 0; i < 2; ++i)
#pragma unroll
    for (int j = 0; j < 5; ++j) acc[i][j] = (f32x4){0.f, 0.f, 0.f, 0.f};

  const u16* fb = featP + (size_t)b * PB;
  const u16* Ab = Awx + (size_t)b * 9 * 192 * 192;

  for (int c = 0; c < 3; ++c) {                    // 64-ch K chunks
    __syncthreads();
#pragma unroll
    for (int it = 0; it < 6; ++it) {
      int idx = it * 384 + tid;
      if (idx < 2016) {
        int slot = idx & 7; int q = (idx >> 3) % 84; int row = idx / 672;
        bf16x8 v = *(const bf16x8*)(fb + ((size_t)(h + 1 + row) * WP + q) * KC + c * 64 + slot * 8);
        int byte = (idx * 16) ^ ((q & 7) << 4);
        *(bf16x8*)(lb + byte) = v;
      }
    }
    __syncthreads();
#pragma unroll
    for (int ty = 0; ty < 3; ++ty)
#pragma unroll
      for (int tx = 0; tx < 3; ++tx) {
        const u16* At = Ab + ((size_t)((ty * 3 + tx) * 192 + wm * 32 + l15)) * 192 + c * 64;
#pragma unroll
        for (int half = 0; half < 2; ++half) {
          bf16x8 av[2], bv[5];
#pragma unroll
          for (int fm = 0; fm < 2; ++fm)
            av[fm] = *(const bf16x8*)(At + fm * 16 * 192 + half * 32 + kq * 8);
#pragma unroll
          for (int fn = 0; fn < 5; ++fn) {
            int q = fn * 16 + l15 + tx + 1;
            int byte = (((ty * 84 + q) * 8 + half * 4 + kq) * 16) ^ ((q & 7) << 4);
            bv[fn] = *(const bf16x8*)(lb + byte);
          }
#pragma unroll
          for (int fm = 0; fm < 2; ++fm)
#pragma unroll
            for (int fn = 0; fn < 5; ++fn)
              acc[fm][fn] = __builtin_amdgcn_mfma_f32_16x16x32_bf16(av[fm], bv[fn], acc[fm][fn], 0, 0, 0);
        }
      }
  }

  // epilogue: relu -> bf16 NHWC padded (rows >=177 are zero by construction)
#pragma unroll
  for (int fm = 0; fm < 2; ++fm) {
    int i0 = wm * 32 + fm * 16 + kq * 4;
#pragma unroll
    for (int fn = 0; fn < 5; ++fn) {
      int ow = fn * 16 + l15;
      u16* dst = outP + ((size_t)(b * HP + h + 2) * WP + (ow + 2)) * KC + i0;
      u16 t0 = f2b(fmaxf(acc[fm][fn][0], 0.f));
      u16 t1 = f2b(fmaxf(acc[fm][fn][1], 0.f));
      u16 t2 = f2b(fmaxf(acc[fm][fn][2], 0.f));
      u16 t3 = f2b(fmaxf(acc[fm][fn][3], 0.f));
      unsigned lo = (unsigned)t0 | ((unsigned)t1 << 16);
      unsigned hi = (unsigned)t2 | ((unsigned)t3 << 16);
      uint2 pk; pk.x = lo; pk.y = hi;
      *(uint2*)dst = pk;
    }
  }
}

// ---------------- MFMA implicit-GEMM conv over padded NHWC bf16 (conv5b) ----------------
template<int TY, int TX, int S, int OH, int OW, int M, int BM, int BN, int POFF,
         int KCIN, int HPIN, int WPIN, int EPI>
__global__ __launch_bounds__(256) void gemm_conv(
    const u16* __restrict__ A, const u16* __restrict__ featP,
    float* __restrict__ outF, int MT, int NT) {
  constexpr int WM = BM / 2, WN = BN / 2, FM = WM / 16, FN = WN / 16;
  constexpr int NKC = KCIN / 32;
  int nwg = gridDim.x;
  int bid = (int)(blockIdx.x % 8) * (nwg / 8) + (int)(blockIdx.x / 8);
  int mt = bid % MT; int rest = bid / MT; int nt = rest % NT; int b = rest / NT;
  int lane = threadIdx.x & 63; int wv = threadIdx.x >> 6;
  int wm = wv >> 1, wn = wv & 1;
  int l15 = lane & 15, kq = lane >> 4;

  f32x4 acc[FM][FN];
#pragma unroll
  for (int i = 0; i < FM; ++i)
#pragma unroll
    for (int j = 0; j < FN; ++j) acc[i][j] = (f32x4){0.f, 0.f, 0.f, 0.f};

  const u16* Abase = A + (size_t)(mt * BM + wm * WM + l15) * KCIN + kq * 8;
  const u16* fb = featP + (size_t)b * (HPIN * WPIN * KCIN) + kq * 8;

  int ohh[FN], oww[FN];
#pragma unroll
  for (int fn = 0; fn < FN; ++fn) {
    int p = nt * BN + wn * WN + fn * 16 + l15;
    ohh[fn] = p / OW; oww[fn] = p % OW;
  }

  for (int kc = 0; kc < NKC; ++kc) {
    for (int ty = 0; ty < TY; ++ty)
      for (int tx = 0; tx < TX; ++tx) {
        const u16* At = Abase + (size_t)((ty * TX + tx) * M) * KCIN + kc * 32;
        bf16x8 av[FM], bv[FN];
#pragma unroll
        for (int fm = 0; fm < FM; ++fm)
          av[fm] = *(const bf16x8*)(At + fm * 16 * KCIN);
#pragma unroll
        for (int fn = 0; fn < FN; ++fn) {
          int hi = ohh[fn] * S + ty + POFF;
          int wi = oww[fn] * S + tx + POFF;
          bv[fn] = *(const bf16x8*)(fb + (size_t)(hi * WPIN + wi) * KCIN + kc * 32);
        }
#pragma unroll
        for (int fm = 0; fm < FM; ++fm)
#pragma unroll
          for (int fn = 0; fn < FN; ++fn)
            acc[fm][fn] = __builtin_amdgcn_mfma_f32_16x16x32_bf16(av[fm], bv[fn], acc[fm][fn], 0, 0, 0);
      }
  }

#pragma unroll
  for (int fm = 0; fm < FM; ++fm) {
    int oc0 = mt * BM + wm * WM + fm * 16 + kq * 4;
#pragma unroll
    for (int fn = 0; fn < FN; ++fn) {
#pragma unroll
      for (int r = 0; r < 4; ++r) {
        float v = fmaxf(acc[fm][fn][r], 0.f);
        outF[(((size_t)b * M + oc0 + r) * OH + ohh[fn]) * OW + oww[fn]] = v;
      }
    }
  }
}

// ---------------- conv3+mean fold, step 1: 9-bin tap sums of hb ----------------
__global__ void tapsum_kernel(const float* __restrict__ hb, float* __restrict__ Sm) {
  int b = blockIdx.x >> 6; int ic = blockIdx.x & 63; int lane = threadIdx.x;
  const float* p = hb + ((size_t)(b * 64 + ic)) * 320;
  float s[9];
#pragma unroll
  for (int t = 0; t < 9; ++t) s[t] = 0.f;
  for (int i = lane; i < 320; i += 64) {
    int ih = i / 20, iw = i % 20;
    float v = p[i];
#pragma unroll
    for (int ky = 0; ky < 3; ++ky) {
      int t2 = ih + 1 - ky;
      if (t2 < 0 || t2 > 14 || (t2 & 1)) continue;
#pragma unroll
      for (int kx = 0; kx < 3; ++kx) {
        int t3 = iw + 1 - kx;
        if (t3 < 0 || t3 > 18 || (t3 & 1)) continue;
        s[ky * 3 + kx] += v;
      }
    }
  }
#pragma unroll
  for (int t = 0; t < 9; ++t)
#pragma unroll
    for (int off = 32; off > 0; off >>= 1) s[t] += __shfl_down(s[t], off);
  if (lane == 0) {
#pragma unroll
    for (int t = 0; t < 9; ++t) Sm[(b * 64 + ic) * 9 + t] = s[t];
  }
}

// ---------------- step 2: fv[b][o] = (1/80) * sum_{ic,t} w3[o,ic,t]*S[b,ic,t] ----------------
__global__ void gemv_fv(const float* __restrict__ w3, const float* __restrict__ Sm,
                        float* __restrict__ fv, int OC) {
  int o = blockIdx.x % OC; int b = blockIdx.x / OC; int lane = threadIdx.x;
  const float* wp = w3 + ((size_t)o * 64 + lane) * 9;
  const float* sp = Sm + ((size_t)b * 64 + lane) * 9;
  float acc = 0.f;
#pragma unroll
  for (int t = 0; t < 9; ++t) acc += wp[t] * sp[t];
#pragma unroll
  for (int off = 32; off > 0; off >>= 1) acc += __shfl_down(acc, off);
  if (lane == 0) fv[b * OC + o] = acc * (1.0f / 80.0f);
}

// ---------------- final: out = fv2*wxf_w + wxf_b ----------------
__global__ void final_kernel(const float* __restrict__ fv, const float* __restrict__ ww,
                             const float* __restrict__ wb, float* __restrict__ out) {
  int idx = blockIdx.x * blockDim.x + threadIdx.x;
  if (idx >= B * 64 * 576) return;
  int kk = idx % 576; int i = (idx / 576) % 64; int b = idx / (576 * 64);
  out[idx] = fv[b * 64 + i] * ww[i * 576 + kk] + wb[i * 576 + kk];
}

extern "C" void kernel_launch(void* const* d_in, const int* in_sizes, int n_in,
                              void* d_out, int out_size, void* d_ws, size_t ws_size,
                              hipStream_t stream) {
  const float* x0    = (const float*)d_in[0];
  const float* y0    = (const float*)d_in[1];
  const float* x     = (const float*)d_in[2];
  const float* y     = (const float*)d_in[3];
  const float* w1a   = (const float*)d_in[4];
  const float* w1b   = (const float*)d_in[5];
  const float* w1c   = (const float*)d_in[6];
  const float* w2a   = (const float*)d_in[7];
  const float* w2b   = (const float*)d_in[8];
  const float* w2c   = (const float*)d_in[9];
  const float* wx_w  = (const float*)d_in[10];
  const float* wx_b  = (const float*)d_in[11];
  const float* wxf_w = (const float*)d_in[12];
  const float* wxf_b = (const float*)d_in[13];
  float* out = (float*)d_out;

  char* base = (char*)d_ws;
  size_t off = 0;
  auto take = [&](size_t bytes) -> char* {
    char* p = base + off; off += (bytes + 255) & ~(size_t)255; return p;
  };
  u16*   featP1 = (u16*)take((size_t)B * PB * 2);
  float* xpT    = (float*)take((size_t)B * H * W * C * 4);
  float* ypT    = (float*)take((size_t)B * H * W * C * 4);
  u16*   featP2 = (u16*)(void*)xpT;                 // alias: 21 MB >= 17.55 MB
  u16*   Awx    = (u16*)take((size_t)B * 9 * 192 * 192 * 2);
  u16*   A5a    = (u16*)take((size_t)25 * 64 * 192 * 2);
  u16*   A5b    = (u16*)take((size_t)25 * 64 * 192 * 2);
  u16*   A5b1   = (u16*)take((size_t)25 * 64 * 64 * 2);
  u16*   A5b2   = (u16*)take((size_t)25 * 64 * 64 * 2);
  u16*   haP    = (u16*)take((size_t)B * HA * WA * 64 * 2);
  float* pa     = (float*)take((size_t)5 * B * 32 * 40 * 64 * 4);
  float* hb     = (float*)take((size_t)B * 64 * 320 * 4);
  float* Sm     = (float*)take((size_t)B * 64 * 9 * 4);
  float* fv1    = (float*)take((size_t)B * CW * 4);
  float* fv2    = (float*)take((size_t)B * 64 * 4);
  if (off > ws_size) return;

  const int TB = 256;
  int nfull8 = (B * PB) / 8;
  int nha8 = (B * HA * WA * 64) / 8;

  zfill8<<<(nfull8 + TB - 1) / TB, TB, 0, stream>>>(featP1, nfull8);
  zfill8<<<(nha8 + TB - 1) / TB, TB, 0, stream>>>(haP, nha8);
  {
    int n = 2 * B * C * H * W;
    pool2_nhwc<<<(n + TB - 1) / TB, TB, 0, stream>>>(x0, y0, xpT, ypT);
  }
  {
    int n = B * H * W * 49;
    corr_fill<<<(n + TB - 1) / TB, TB, 0, stream>>>(xpT, ypT, featP1);
    int n2 = B * 128 * H * W;
    copyxy<<<(n2 + TB - 1) / TB, TB, 0, stream>>>(x, y, featP1);
  }
  zfill8<<<(nfull8 + TB - 1) / TB, TB, 0, stream>>>(featP2, nfull8);
  pack_w5<<<(25 * 64 * 192 + TB - 1) / TB, TB, 0, stream>>>(w1a, A5a, 192, CW);
  pack_w5<<<(25 * 64 * 192 + TB - 1) / TB, TB, 0, stream>>>(w2a, A5b, 192, CW);
  pack_w5<<<(25 * 64 * 64 + TB - 1) / TB, TB, 0, stream>>>(w1b, A5b1, 64, 64);
  pack_w5<<<(25 * 64 * 64 + TB - 1) / TB, TB, 0, stream>>>(w2b, A5b2, 64, 64);

  // ---- branch 1 ----
  conv5_split_kernel<<<640, 128, 0, stream>>>(A5a, featP1, pa);
  combine5<<<(B * 32 * 40 * 64 + TB - 1) / TB, TB, 0, stream>>>(pa, haP);
  gemm_conv<5, 5, 2, 16, 20, 64, 64, 64, 0, 64, HA, WA, 0>
      <<<5 * B, TB, 0, stream>>>(A5b1, haP, hb, 1, 5);
  tapsum_kernel<<<B * 64, 64, 0, stream>>>(hb, Sm);
  gemv_fv<<<B * CW, 64, 0, stream>>>(w1c, Sm, fv1, CW);

  // ---- adaptive conv (per-batch wx, M=192) ----
  wx_pack<<<(B * 9 * 192 * 192 + TB - 1) / TB, TB, 0, stream>>>(fv1, wx_w, wx_b, Awx);
  ad_conv_kernel<<<64 * B, 384, 0, stream>>>(Awx, featP1, featP2);

  // ---- branch 2 ----
  conv5_split_kernel<<<640, 128, 0, stream>>>(A5b, featP2, pa);
  combine5<<<(B * 32 * 40 * 64 + TB - 1) / TB, TB, 0, stream>>>(pa, haP);
  gemm_conv<5, 5, 2, 16, 20, 64, 64, 64, 0, 64, HA, WA, 0>
      <<<5 * B, TB, 0, stream>>>(A5b2, haP, hb, 1, 5);
  tapsum_kernel<<<B * 64, 64, 0, stream>>>(hb, Sm);
  gemv_fv<<<B * 64, 64, 0, stream>>>(w2c, Sm, fv2, 64);

  // ---- final output ----
  final_kernel<<<(B * 64 * 576 + TB - 1) / TB, TB, 0, stream>>>(fv2, wxf_w, wxf_b, out);
}

// Round 7
// 272.222 us; speedup vs baseline: 29.5869x; 1.3254x over previous
//
#include <hip/hip_runtime.h>

typedef unsigned short u16;
typedef __attribute__((ext_vector_type(8))) short bf16x8;
typedef __attribute__((ext_vector_type(4))) float f32x4;

static constexpr int B  = 8;
static constexpr int C  = 64;
static constexpr int CW = 177;
static constexpr int H  = 64, W  = 80;
static constexpr int HP = 68, WP = 84, KC = 192;   // feat padded NHWC
static constexpr int PB = HP * WP * KC;
static constexpr int HA = 36, WA = 44;             // conv5a out padded

__device__ __forceinline__ u16 f2b(float f) {
  union { float f; unsigned u; } v; v.f = f;
  unsigned u = v.u;
  return (u16)((u + 0x7FFF + ((u >> 16) & 1)) >> 16);
}
__device__ __forceinline__ float blo(unsigned u) {
  union { unsigned v; float f; } t; t.v = u << 16; return t.f;
}
__device__ __forceinline__ float bhi(unsigned u) {
  union { unsigned v; float f; } t; t.v = u & 0xffff0000u; return t.f;
}
__device__ __forceinline__ unsigned pk2(u16 a, u16 b) {
  return (unsigned)a | ((unsigned)b << 16);
}

// ---------------- zero-fill two buffers ----------------
__global__ void zfill2(u16* __restrict__ p1, int n1, u16* __restrict__ p2, int n2) {
  int i = blockIdx.x * blockDim.x + threadIdx.x;
  bf16x8 z = 0;
  if (i < n1) ((bf16x8*)p1)[i] = z;
  else if (i < n1 + n2) ((bf16x8*)p2)[i - n1] = z;
}

// ---------------- pool 2x2 -> bf16 NHWC via LDS transpose ----------------
__global__ __launch_bounds__(256) void pool2_kernel(const float* __restrict__ x0, const float* __restrict__ y0,
                                                    u16* __restrict__ xpT, u16* __restrict__ ypT) {
  __shared__ u16 lt[80][66];
  int blk = blockIdx.x;
  int sel = blk & 1; int h = (blk >> 1) & 63; int b = blk >> 7;
  const float* in = sel ? y0 : x0;
  u16* out = sel ? ypT : xpT;
  int tid = threadIdx.x;
#pragma unroll
  for (int i = 0; i < 20; ++i) {
    int e = i * 256 + tid;                    // 5120 = 64c x 80w
    int c = e / 80, w = e % 80;
    const float* p = in + ((size_t)(b * 64 + c) * 128 + 2 * h) * 160 + 2 * w;
    float2 r0 = *(const float2*)p;
    float2 r1 = *(const float2*)(p + 160);
    lt[w][c] = f2b(0.25f * (r0.x + r0.y + r1.x + r1.y));
  }
  __syncthreads();
#pragma unroll
  for (int i = 0; i < 20; ++i) {
    int e = i * 256 + tid;
    int w = e / 64, c = e % 64;
    out[((size_t)(b * H + h) * W + w) * C + c] = lt[w][c];
  }
}

// ---------------- corr (bf16 pools) -> featP channels 0..48 ----------------
__global__ void corr_fill(const u16* __restrict__ xpT, const u16* __restrict__ ypT,
                          u16* __restrict__ featP) {
  int idx = blockIdx.x * blockDim.x + threadIdx.x;
  if (idx >= B * H * W * 49) return;
  int o = idx % 49; int p = idx / 49;
  int w = p % W; int h = (p / W) % H; int b = p / (W * H);
  int dy = (o / 7) * 2 - 6, dx = (o % 7) * 2 - 6;
  int hh = h + dy, ww = w + dx;
  float s = 0.f;
  if (hh >= 0 && hh < H && ww >= 0 && ww < W) {
    const uint4* xv = (const uint4*)(xpT + ((size_t)(b * H + h) * W + w) * C);
    const uint4* yv = (const uint4*)(ypT + ((size_t)(b * H + hh) * W + ww) * C);
#pragma unroll
    for (int i = 0; i < 8; ++i) {
      uint4 a = xv[i], q = yv[i];
      s += blo(a.x) * blo(q.x) + bhi(a.x) * bhi(q.x);
      s += blo(a.y) * blo(q.y) + bhi(a.y) * bhi(q.y);
      s += blo(a.z) * blo(q.z) + bhi(a.z) * bhi(q.z);
      s += blo(a.w) * blo(q.w) + bhi(a.w) * bhi(q.w);
    }
  }
  s *= (1.0f / 64.0f);
  featP[((size_t)(b * HP + h + 2) * WP + (w + 2)) * KC + o] = f2b(s);
}

// ---------------- x,y -> featP ch 49..176 via LDS transpose ----------------
__global__ __launch_bounds__(256) void copy_tr(const float* __restrict__ x, const float* __restrict__ y,
                                               u16* __restrict__ featP) {
  __shared__ float lt[40][129];
  int blk = blockIdx.x;
  int half = blk & 1; int h = (blk >> 1) & 63; int b = blk >> 7;
  int tid = threadIdx.x;
#pragma unroll
  for (int i = 0; i < 20; ++i) {
    int e = i * 256 + tid;                    // 5120 = 128c x 40w
    int c2 = e / 40, w = e % 40;
    const float* src = (c2 < 64) ? x : y;
    int c = c2 & 63;
    lt[w][c2] = src[((size_t)(b * 64 + c) * H + h) * W + half * 40 + w];
  }
  __syncthreads();
#pragma unroll
  for (int i = 0; i < 20; ++i) {
    int e = i * 256 + tid;
    int wr = e / 128, c = e % 128;
    featP[((size_t)(b * HP + h + 2) * WP + (half * 40 + wr + 2)) * KC + 49 + c] = f2b(lt[wr][c]);
  }
}

// ---------------- pack all four 5x5 weights ----------------
__global__ void pack_all(const float* __restrict__ w1a, const float* __restrict__ w2a,
                         const float* __restrict__ w1b, const float* __restrict__ w2b,
                         u16* __restrict__ A5a, u16* __restrict__ A5b,
                         u16* __restrict__ A5b1, u16* __restrict__ A5b2) {
  int idx = blockIdx.x * blockDim.x + threadIdx.x;
  const int s1 = 25 * 64 * 192, s2 = 25 * 64 * 64;
  if (idx < 2 * s1) {
    const float* w = idx < s1 ? w1a : w2a; u16* A = idx < s1 ? A5a : A5b;
    int e = idx % s1;
    int j = e % 192; int i = (e / 192) % 64; int kk = e / (192 * 64);
    int ky = kk / 5, kx = kk % 5;
    float v = (j < CW) ? w[(((size_t)i * CW + j) * 5 + ky) * 5 + kx] : 0.f;
    A[e] = f2b(v);
  } else if (idx < 2 * s1 + 2 * s2) {
    int t = idx - 2 * s1;
    const float* w = t < s2 ? w1b : w2b; u16* A = t < s2 ? A5b1 : A5b2;
    int e = t % s2;
    int j = e % 64; int i = (e / 64) % 64; int kk = e / (64 * 64);
    int ky = kk / 5, kx = kk % 5;
    A[e] = f2b(w[(((size_t)i * 64 + j) * 5 + ky) * 5 + kx]);
  }
}

// ---------------- halo-only zero fill for featP2 ----------------
__global__ void halo_fill(u16* __restrict__ featP) {
  int idx = blockIdx.x * blockDim.x + threadIdx.x;
  if (idx >= B * 592 * 24) return;
  int ch = idx % 24; int pi = (idx / 24) % 592; int b = idx / (24 * 592);
  int row, col;
  if (pi < 336) {
    int r = pi / 84; row = (r < 2) ? r : r + 64; col = pi % 84;
  } else {
    int pj = pi - 336; row = 2 + (pj >> 2);
    int cc = pj & 3; col = (cc < 2) ? cc : cc + 80;
  }
  bf16x8 z = 0;
  *(bf16x8*)(featP + ((size_t)(b * HP + row) * WP + col) * KC + ch * 8) = z;
}

// ---------------- per-batch adaptive weights, read ww/wb once ----------------
__global__ void wx_pack(const float* __restrict__ fv, const float* __restrict__ ww,
                        const float* __restrict__ wb, u16* __restrict__ Awx) {
  int idx = blockIdx.x * blockDim.x + threadIdx.x;
  if (idx >= 9 * 192 * 24) return;
  int j8 = idx % 24; int i = (idx / 24) % 192; int kk = idx / (24 * 192);
  float wwv[8], wbv[8];
#pragma unroll
  for (int jj = 0; jj < 8; ++jj) {
    int j = j8 * 8 + jj;
    if (i < CW && j < CW) {
      size_t o = ((size_t)i * CW + j) * 9 + kk;
      wwv[jj] = ww[o]; wbv[jj] = wb[o];
    } else { wwv[jj] = 0.f; wbv[jj] = 0.f; }
  }
  for (int b = 0; b < B; ++b) {
    float f = (i < CW) ? fv[b * CW + i] : 0.f;
    u16 o[8];
#pragma unroll
    for (int jj = 0; jj < 8; ++jj) o[jj] = f2b(f * wwv[jj] + wbv[jj]);
    uint4 v; v.x = pk2(o[0], o[1]); v.y = pk2(o[2], o[3]); v.z = pk2(o[4], o[5]); v.w = pk2(o[6], o[7]);
    *(uint4*)(Awx + (size_t)b * 331776 + (size_t)kk * 36864 + (size_t)i * 192 + j8 * 8) = v;
  }
}

// ---------------- adaptive conv v4: FM=4 x FN=3, A-prefetch, 6 waves ----------------
__global__ __launch_bounds__(384, 3) void ad_conv_kernel(
    const u16* __restrict__ Awx, const u16* __restrict__ featP, u16* __restrict__ outP) {
  __shared__ u16 lds[3 * 84 * 64];                 // 32256 B
  char* lb = (char*)lds;
  int bid = (int)(blockIdx.x % 8) * 64 + (int)(blockIdx.x / 8);
  int h = bid & 63; int b = bid >> 6;
  int tid = threadIdx.x;
  int lane = tid & 63; int wv = tid >> 6;
  int wm = wv % 3; int nsel = wv / 3;              // 3 M-groups x 2 N-halves
  int n0 = nsel * 40;
  int l15 = lane & 15, kq = lane >> 4;

  f32x4 acc[4][3];
#pragma unroll
  for (int i = 0; i < 4; ++i)
#pragma unroll
    for (int j = 0; j < 3; ++j) acc[i][j] = (f32x4){0.f, 0.f, 0.f, 0.f};

  const u16* fb = featP + (size_t)b * PB;
  const u16* Ab = Awx + (size_t)b * 331776 + (size_t)(wm * 64 + l15) * 192 + kq * 8;

  bf16x8 avc[4], avn[4];
#pragma unroll
  for (int fm = 0; fm < 4; ++fm)
    avc[fm] = *(const bf16x8*)(Ab + fm * 16 * 192);

#pragma unroll
  for (int c = 0; c < 3; ++c) {
    __syncthreads();
#pragma unroll
    for (int it = 0; it < 6; ++it) {
      int idx = it * 384 + tid;
      if (idx < 2016) {
        int slot = idx & 7; int q = (idx >> 3) % 84; int row = idx / 672;
        bf16x8 v = *(const bf16x8*)(fb + ((size_t)(h + 1 + row) * WP + q) * KC + c * 64 + slot * 8);
        int byte = (idx * 16) ^ ((q & 7) << 4);
        *(bf16x8*)(lb + byte) = v;
      }
    }
    __syncthreads();
#pragma unroll
    for (int ph = 0; ph < 18; ++ph) {
      // prefetch next phase's A fragments
      {
        int nc = c, nph = ph + 1;
        if (ph == 17) { nc = c + 1; nph = 0; }
        if (nc < 3) {
          int ntap = nph >> 1, nhalf = nph & 1;
          const u16* At = Ab + (size_t)ntap * 36864 + nc * 64 + nhalf * 32;
#pragma unroll
          for (int fm = 0; fm < 4; ++fm) avn[fm] = *(const bf16x8*)(At + fm * 16 * 192);
        }
      }
      int tap = ph >> 1, half = ph & 1;
      int ty = tap / 3, tx = tap % 3;
      bf16x8 bv[3];
#pragma unroll
      for (int fn = 0; fn < 3; ++fn) {
        int q = n0 + fn * 16 + l15 + tx + 1;
        q = q > 83 ? 83 : q;
        int byte = (((ty * 84 + q) * 8 + half * 4 + kq) * 16) ^ ((q & 7) << 4);
        bv[fn] = *(const bf16x8*)(lb + byte);
      }
#pragma unroll
      for (int fm = 0; fm < 4; ++fm)
#pragma unroll
        for (int fn = 0; fn < 3; ++fn)
          acc[fm][fn] = __builtin_amdgcn_mfma_f32_16x16x32_bf16(avc[fm], bv[fn], acc[fm][fn], 0, 0, 0);
#pragma unroll
      for (int fm = 0; fm < 4; ++fm) avc[fm] = avn[fm];
    }
  }

#pragma unroll
  for (int fm = 0; fm < 4; ++fm) {
    int i0 = wm * 64 + fm * 16 + kq * 4;
#pragma unroll
    for (int fn = 0; fn < 3; ++fn) {
      int owr = fn * 16 + l15;
      if (owr < 40) {
        u16* dst = outP + ((size_t)(b * HP + h + 2) * WP + (n0 + owr + 2)) * KC + i0;
        uint2 pkv;
        pkv.x = pk2(f2b(fmaxf(acc[fm][fn][0], 0.f)), f2b(fmaxf(acc[fm][fn][1], 0.f)));
        pkv.y = pk2(f2b(fmaxf(acc[fm][fn][2], 0.f)), f2b(fmaxf(acc[fm][fn][3], 0.f)));
        *(uint2*)dst = pkv;
      }
    }
  }
}

// ---------------- conv5 (s2) ky+c split: one (ky, 3-kc-chunk) per block ----------------
__global__ __launch_bounds__(128, 3) void conv5_split_kernel(
    const u16* __restrict__ A5, const u16* __restrict__ featP, u16* __restrict__ pa) {
  __shared__ u16 lds[2 * 84 * 32];                 // 10.5 KB
  char* lb = (char*)lds;
  int bid = (int)(blockIdx.x % 8) * 160 + (int)(blockIdx.x / 8);
  int rp = bid % 16; int ty = (bid / 16) % 5; int csel = (bid / 80) % 2; int b = bid / 160;
  int r0 = rp * 2;
  int kc0 = csel * 3;
  int tid = threadIdx.x;
  int lane = tid & 63; int wm = tid >> 6;          // 2 waves
  int l15 = lane & 15, kq = lane >> 4;

  f32x4 acc[2][5];
#pragma unroll
  for (int i = 0; i < 2; ++i)
#pragma unroll
    for (int j = 0; j < 5; ++j) acc[i][j] = (f32x4){0.f, 0.f, 0.f, 0.f};

  const u16* fb = featP + (size_t)b * PB;
  int rowg0 = 2 * r0 + ty;

#pragma unroll
  for (int k = 0; k < 3; ++k) {
    int kc = kc0 + k;
    __syncthreads();
#pragma unroll
    for (int it = 0; it < 6; ++it) {
      int idx = it * 128 + tid;
      if (idx < 672) {
        int slot = idx & 3; int q = (idx >> 2) % 84; int row = idx / 336;
        bf16x8 v = *(const bf16x8*)(fb + ((size_t)(rowg0 + 2 * row) * WP + q) * KC + kc * 32 + slot * 8);
        int byte = (idx * 16) ^ ((q & 7) << 4);
        *(bf16x8*)(lb + byte) = v;
      }
    }
    __syncthreads();
#pragma unroll
    for (int tx = 0; tx < 5; ++tx) {
      bf16x8 av[2], bv[5];
#pragma unroll
      for (int fm = 0; fm < 2; ++fm)
        av[fm] = *(const bf16x8*)(A5 + ((size_t)((ty * 5 + tx) * 64 + wm * 32 + fm * 16 + l15)) * 192 + kc * 32 + kq * 8);
#pragma unroll
      for (int fn = 0; fn < 5; ++fn) {
        int p = fn * 16 + l15;
        int orow = p / 40, ocol = p % 40;
        int q = ocol * 2 + tx;
        int byte = (((orow * 84 + q) * 4 + kq) * 16) ^ ((q & 7) << 4);
        bv[fn] = *(const bf16x8*)(lb + byte);
      }
#pragma unroll
      for (int fm = 0; fm < 2; ++fm)
#pragma unroll
        for (int fn = 0; fn < 5; ++fn)
          acc[fm][fn] = __builtin_amdgcn_mfma_f32_16x16x32_bf16(av[fm], bv[fn], acc[fm][fn], 0, 0, 0);
    }
  }
  int slot10 = csel * 5 + ty;
#pragma unroll
  for (int fm = 0; fm < 2; ++fm) {
    int oc0 = wm * 32 + fm * 16 + kq * 4;
#pragma unroll
    for (int fn = 0; fn < 5; ++fn) {
      int p = fn * 16 + l15;
      int orow = r0 + p / 40, ocol = p % 40;
      u16* dst = pa + (((((size_t)slot10 * B + b) * 32 + orow) * 40 + ocol) * 64) + oc0;
      uint2 pkv;
      pkv.x = pk2(f2b(acc[fm][fn][0]), f2b(acc[fm][fn][1]));
      pkv.y = pk2(f2b(acc[fm][fn][2]), f2b(acc[fm][fn][3]));
      *(uint2*)dst = pkv;
    }
  }
}

// ---------------- combine 10 bf16 partials -> relu -> bf16 haP ----------------
__global__ void combine10(const u16* __restrict__ pa, u16* __restrict__ haP) {
  int idx = blockIdx.x * blockDim.x + threadIdx.x;
  if (idx >= B * 32 * 40 * 8) return;
  int c8 = idx & 7; int t = idx >> 3;
  int ocol = t % 40; t /= 40; int orow = t % 32; int b = t / 32;
  float s[8];
#pragma unroll
  for (int k = 0; k < 8; ++k) s[k] = 0.f;
#pragma unroll
  for (int sl = 0; sl < 10; ++sl) {
    const u16* p = pa + ((((size_t)sl * B + b) * 32 + orow) * 40 + ocol) * 64 + c8 * 8;
    uint4 v = *(const uint4*)p;
    s[0] += blo(v.x); s[1] += bhi(v.x); s[2] += blo(v.y); s[3] += bhi(v.y);
    s[4] += blo(v.z); s[5] += bhi(v.z); s[6] += blo(v.w); s[7] += bhi(v.w);
  }
  uint4 o;
  o.x = pk2(f2b(fmaxf(s[0], 0.f)), f2b(fmaxf(s[1], 0.f)));
  o.y = pk2(f2b(fmaxf(s[2], 0.f)), f2b(fmaxf(s[3], 0.f)));
  o.z = pk2(f2b(fmaxf(s[4], 0.f)), f2b(fmaxf(s[5], 0.f)));
  o.w = pk2(f2b(fmaxf(s[6], 0.f)), f2b(fmaxf(s[7], 0.f)));
  *(uint4*)(haP + ((size_t)(b * HA + orow + 2) * WA + (ocol + 2)) * 64 + c8 * 8) = o;
}

// ---------------- MFMA implicit-GEMM conv (conv5b) ----------------
template<int TY, int TX, int S, int OH, int OW, int M, int BM, int BN, int POFF,
         int KCIN, int HPIN, int WPIN>
__global__ __launch_bounds__(256) void gemm_conv(
    const u16* __restrict__ A, const u16* __restrict__ featP,
    float* __restrict__ outF, int MT, int NT) {
  constexpr int WM = BM / 2, WN = BN / 2, FM = WM / 16, FN = WN / 16;
  constexpr int NKC = KCIN / 32;
  int nwg = gridDim.x;
  int bid = (int)(blockIdx.x % 8) * (nwg / 8) + (int)(blockIdx.x / 8);
  int mt = bid % MT; int rest = bid / MT; int nt = rest % NT; int b = rest / NT;
  int lane = threadIdx.x & 63; int wv = threadIdx.x >> 6;
  int wm = wv >> 1, wn = wv & 1;
  int l15 = lane & 15, kq = lane >> 4;

  f32x4 acc[FM][FN];
#pragma unroll
  for (int i = 0; i < FM; ++i)
#pragma unroll
    for (int j = 0; j < FN; ++j) acc[i][j] = (f32x4){0.f, 0.f, 0.f, 0.f};

  const u16* Abase = A + (size_t)(mt * BM + wm * WM + l15) * KCIN + kq * 8;
  const u16* fb = featP + (size_t)b * (HPIN * WPIN * KCIN) + kq * 8;

  int ohh[FN], oww[FN];
#pragma unroll
  for (int fn = 0; fn < FN; ++fn) {
    int p = nt * BN + wn * WN + fn * 16 + l15;
    ohh[fn] = p / OW; oww[fn] = p % OW;
  }

  for (int kc = 0; kc < NKC; ++kc) {
    for (int ty = 0; ty < TY; ++ty)
      for (int tx = 0; tx < TX; ++tx) {
        const u16* At = Abase + (size_t)((ty * TX + tx) * M) * KCIN + kc * 32;
        bf16x8 av[FM], bv[FN];
#pragma unroll
        for (int fm = 0; fm < FM; ++fm)
          av[fm] = *(const bf16x8*)(At + fm * 16 * KCIN);
#pragma unroll
        for (int fn = 0; fn < FN; ++fn) {
          int hi = ohh[fn] * S + ty + POFF;
          int wi = oww[fn] * S + tx + POFF;
          bv[fn] = *(const bf16x8*)(fb + (size_t)(hi * WPIN + wi) * KCIN + kc * 32);
        }
#pragma unroll
        for (int fm = 0; fm < FM; ++fm)
#pragma unroll
          for (int fn = 0; fn < FN; ++fn)
            acc[fm][fn] = __builtin_amdgcn_mfma_f32_16x16x32_bf16(av[fm], bv[fn], acc[fm][fn], 0, 0, 0);
      }
  }

#pragma unroll
  for (int fm = 0; fm < FM; ++fm) {
    int oc0 = mt * BM + wm * WM + fm * 16 + kq * 4;
#pragma unroll
    for (int fn = 0; fn < FN; ++fn) {
#pragma unroll
      for (int r = 0; r < 4; ++r) {
        float v = fmaxf(acc[fm][fn][r], 0.f);
        outF[(((size_t)b * M + oc0 + r) * OH + ohh[fn]) * OW + oww[fn]] = v;
      }
    }
  }
}

// ---------------- conv3+mean fold, step 1 ----------------
__global__ void tapsum_kernel(const float* __restrict__ hb, float* __restrict__ Sm) {
  int b = blockIdx.x >> 6; int ic = blockIdx.x & 63; int lane = threadIdx.x;
  const float* p = hb + ((size_t)(b * 64 + ic)) * 320;
  float s[9];
#pragma unroll
  for (int t = 0; t < 9; ++t) s[t] = 0.f;
  for (int i = lane; i < 320; i += 64) {
    int ih = i / 20, iw = i % 20;
    float v = p[i];
#pragma unroll
    for (int ky = 0; ky < 3; ++ky) {
      int t2 = ih + 1 - ky;
      if (t2 < 0 || t2 > 14 || (t2 & 1)) continue;
#pragma unroll
      for (int kx = 0; kx < 3; ++kx) {
        int t3 = iw + 1 - kx;
        if (t3 < 0 || t3 > 18 || (t3 & 1)) continue;
        s[ky * 3 + kx] += v;
      }
    }
  }
#pragma unroll
  for (int t = 0; t < 9; ++t)
#pragma unroll
    for (int off = 32; off > 0; off >>= 1) s[t] += __shfl_down(s[t], off);
  if (lane == 0) {
#pragma unroll
    for (int t = 0; t < 9; ++t) Sm[(b * 64 + ic) * 9 + t] = s[t];
  }
}

// ---------------- step 2: fv GEMV ----------------
__global__ void gemv_fv(const float* __restrict__ w3, const float* __restrict__ Sm,
                        float* __restrict__ fv, int OC) {
  int o = blockIdx.x % OC; int b = blockIdx.x / OC; int lane = threadIdx.x;
  const float* wp = w3 + ((size_t)o * 64 + lane) * 9;
  const float* sp = Sm + ((size_t)b * 64 + lane) * 9;
  float acc = 0.f;
#pragma unroll
  for (int t = 0; t < 9; ++t) acc += wp[t] * sp[t];
#pragma unroll
  for (int off = 32; off > 0; off >>= 1) acc += __shfl_down(acc, off);
  if (lane == 0) fv[b * OC + o] = acc * (1.0f / 80.0f);
}

// ---------------- final ----------------
__global__ void final_kernel(const float* __restrict__ fv, const float* __restrict__ ww,
                             const float* __restrict__ wb, float* __restrict__ out) {
  int idx = blockIdx.x * blockDim.x + threadIdx.x;
  if (idx >= B * 64 * 576) return;
  int kk = idx % 576; int i = (idx / 576) % 64; int b = idx / (576 * 64);
  out[idx] = fv[b * 64 + i] * ww[i * 576 + kk] + wb[i * 576 + kk];
}

extern "C" void kernel_launch(void* const* d_in, const int* in_sizes, int n_in,
                              void* d_out, int out_size, void* d_ws, size_t ws_size,
                              hipStream_t stream) {
  const float* x0    = (const float*)d_in[0];
  const float* y0    = (const float*)d_in[1];
  const float* x     = (const float*)d_in[2];
  const float* y     = (const float*)d_in[3];
  const float* w1a   = (const float*)d_in[4];
  const float* w1b   = (const float*)d_in[5];
  const float* w1c   = (const float*)d_in[6];
  const float* w2a   = (const float*)d_in[7];
  const float* w2b   = (const float*)d_in[8];
  const float* w2c   = (const float*)d_in[9];
  const float* wx_w  = (const float*)d_in[10];
  const float* wx_b  = (const float*)d_in[11];
  const float* wxf_w = (const float*)d_in[12];
  const float* wxf_b = (const float*)d_in[13];
  float* out = (float*)d_out;

  char* base = (char*)d_ws;
  size_t off = 0;
  auto take = [&](size_t bytes) -> char* {
    char* p = base + off; off += (bytes + 255) & ~(size_t)255; return p;
  };
  u16*   featP1 = (u16*)take((size_t)B * PB * 2);                 // 17.55 MB
  u16*   featP2 = (u16*)take((size_t)B * PB * 2);                 // 17.55 MB
  u16*   xpT    = featP2;                                          // alias (consumed before featP2 written)
  u16*   ypT    = featP2 + (size_t)B * H * W * C;
  u16*   paAwx  = (u16*)take((size_t)10 * B * 32 * 40 * 64 * 2);  // 13.1 MB (pa; Awx aliases)
  u16*   pa     = paAwx;
  u16*   Awx    = paAwx;
  u16*   A5a    = (u16*)take((size_t)25 * 64 * 192 * 2);
  u16*   A5b    = (u16*)take((size_t)25 * 64 * 192 * 2);
  u16*   A5b1   = (u16*)take((size_t)25 * 64 * 64 * 2);
  u16*   A5b2   = (u16*)take((size_t)25 * 64 * 64 * 2);
  u16*   haP    = (u16*)take((size_t)B * HA * WA * 64 * 2);
  float* hb     = (float*)take((size_t)B * 64 * 320 * 4);
  float* Sm     = (float*)take((size_t)B * 64 * 9 * 4);
  float* fv1    = (float*)take((size_t)B * CW * 4);
  float* fv2    = (float*)take((size_t)B * 64 * 4);
  if (off > ws_size) return;

  const int TB = 256;
  int nf1 = (B * PB) / 8;
  int nha = (B * HA * WA * 64) / 8;

  zfill2<<<(nf1 + nha + TB - 1) / TB, TB, 0, stream>>>(featP1, nf1, haP, nha);
  pool2_kernel<<<B * 64 * 2, TB, 0, stream>>>(x0, y0, xpT, ypT);
  {
    int n = B * H * W * 49;
    corr_fill<<<(n + TB - 1) / TB, TB, 0, stream>>>(xpT, ypT, featP1);
  }
  copy_tr<<<B * 64 * 2, TB, 0, stream>>>(x, y, featP1);
  {
    int n = 2 * 25 * 64 * 192 + 2 * 25 * 64 * 64;
    pack_all<<<(n + TB - 1) / TB, TB, 0, stream>>>(w1a, w2a, w1b, w2b, A5a, A5b, A5b1, A5b2);
  }
  halo_fill<<<(B * 592 * 24 + TB - 1) / TB, TB, 0, stream>>>(featP2);

  // ---- branch 1 ----
  conv5_split_kernel<<<1280, 128, 0, stream>>>(A5a, featP1, pa);
  combine10<<<(B * 32 * 40 * 8 + TB - 1) / TB, TB, 0, stream>>>(pa, haP);
  gemm_conv<5, 5, 2, 16, 20, 64, 32, 32, 0, 64, HA, WA>
      <<<160, TB, 0, stream>>>(A5b1, haP, hb, 2, 10);
  tapsum_kernel<<<B * 64, 64, 0, stream>>>(hb, Sm);
  gemv_fv<<<B * CW, 64, 0, stream>>>(w1c, Sm, fv1, CW);

  // ---- adaptive conv ----
  wx_pack<<<(9 * 192 * 24 + TB - 1) / TB, TB, 0, stream>>>(fv1, wx_w, wx_b, Awx);
  ad_conv_kernel<<<64 * B, 384, 0, stream>>>(Awx, featP1, featP2);

  // ---- branch 2 ----
  conv5_split_kernel<<<1280, 128, 0, stream>>>(A5b, featP2, pa);
  combine10<<<(B * 32 * 40 * 8 + TB - 1) / TB, TB, 0, stream>>>(pa, haP);
  gemm_conv<5, 5, 2, 16, 20, 64, 32, 32, 0, 64, HA, WA>
      <<<160, TB, 0, stream>>>(A5b2, haP, hb, 2, 10);
  tapsum_kernel<<<B * 64, 64, 0, stream>>>(hb, Sm);
  gemv_fv<<<B * 64, 64, 0, stream>>>(w2c, Sm, fv2, 64);

  // ---- final ----
  final_kernel<<<(B * 64 * 576 + TB - 1) / TB, TB, 0, stream>>>(fv2, wxf_w, wxf_b, out);
}